// Round 1
// baseline (2279.831 us; speedup 1.0000x reference)
//
#include <hip/hip_runtime.h>
#include <hip/hip_bf16.h>
#include <math.h>

// Problem constants
#define NTOK   1024
#define PL     512
#define NHEAD  8
#define DHEAD  64
#define BATCH  4
#define ROWS   (BATCH*NTOK)          // 4096
#define QSCALE 0.04419417382415922f  // 1/sqrt(512)

// ---------------------------------------------------------------------------
// qkv GEMM: X[4096,512] @ W[512,1536] + bias -> scatter to Q,K,V [B,H,N,64]
// head split is head-FAST: col c (within a 512 third): d = c>>3, h = c&7
// ---------------------------------------------------------------------------
__global__ __launch_bounds__(256) void qkv_gemm(const float* __restrict__ X,
    const float* __restrict__ W, const float* __restrict__ bias,
    float* __restrict__ Q, float* __restrict__ Kb, float* __restrict__ Vb)
{
    __shared__ float As[16][64];
    __shared__ float Bs[16][64];
    const int tid = threadIdx.x;
    const int tx = tid & 15, ty = tid >> 4;
    const int bm = blockIdx.x, bn = blockIdx.y;
    const int ar = tid >> 2, ac4 = (tid & 3) * 4;
    const int br = tid >> 4, bc4 = (tid & 15) * 4;
    float acc[4][4] = {};
    for (int kt = 0; kt < 512; kt += 16) {
        float4 av = *(const float4*)&X[(size_t)(bm*64 + ar)*512 + kt + ac4];
        float4 bv = *(const float4*)&W[(size_t)(kt + br)*1536 + bn*64 + bc4];
        As[ac4+0][ar]=av.x; As[ac4+1][ar]=av.y; As[ac4+2][ar]=av.z; As[ac4+3][ar]=av.w;
        *(float4*)&Bs[br][bc4] = bv;
        __syncthreads();
        #pragma unroll
        for (int kk = 0; kk < 16; kk++) {
            float4 a4 = *(const float4*)&As[kk][ty*4];
            float4 b4 = *(const float4*)&Bs[kk][tx*4];
            float aa[4] = {a4.x,a4.y,a4.z,a4.w};
            float bb[4] = {b4.x,b4.y,b4.z,b4.w};
            #pragma unroll
            for (int ii=0; ii<4; ii++)
                #pragma unroll
                for (int jj=0; jj<4; jj++) acc[ii][jj] = fmaf(aa[ii], bb[jj], acc[ii][jj]);
        }
        __syncthreads();
    }
    #pragma unroll
    for (int ii=0; ii<4; ii++) {
        const int r = bm*64 + ty*4 + ii;
        const int b = r >> 10, n = r & 1023;
        #pragma unroll
        for (int jj=0; jj<4; jj++) {
            const int c = bn*64 + tx*4 + jj;
            float v = acc[ii][jj] + bias[c];
            const int part = c >> 9;       // 0=q 1=k 2=v (uniform per block)
            const int c2 = c & 511;
            const int h = c2 & 7, d = c2 >> 3;
            const int idx = (((b*NHEAD + h)*NTOK) + n)*DHEAD + d;
            if      (part == 0) Q[idx]  = v * QSCALE;
            else if (part == 1) Kb[idx] = v;
            else                Vb[idx] = v;
        }
    }
}

// ---------------------------------------------------------------------------
// Attention: one block per (b,h,query i).  CAUSAL=1: keys j<=i; else j>=i.
// ---------------------------------------------------------------------------
template<int CAUSAL>
__global__ __launch_bounds__(256) void attn_kernel(const float* __restrict__ Q,
    const float* __restrict__ K, const float* __restrict__ V, float* __restrict__ AO)
{
    __shared__ float qs[64];
    __shared__ float s[1024];
    __shared__ float red[256];
    const int t = threadIdx.x;
    const int bid = blockIdx.x;
    const int i = bid & 1023, h = (bid >> 10) & 7, b = bid >> 13;
    const float* qp = Q + ((size_t)((b*NHEAD + h)*NTOK) + i)*DHEAD;
    const float* kp = K + (size_t)((b*NHEAD + h)*NTOK)*DHEAD;
    const float* vp = V + (size_t)((b*NHEAD + h)*NTOK)*DHEAD;
    if (t < 64) qs[t] = qp[t];
    __syncthreads();
    const int lo = CAUSAL ? 0 : i;
    const int hi = CAUSAL ? i : 1023;
    for (int j = t; j < 1024; j += 256) {
        float sc = -INFINITY;
        if (j >= lo && j <= hi) {
            const float* kr = kp + (size_t)j*64;
            float a = 0.f;
            #pragma unroll
            for (int d = 0; d < 64; d++) a = fmaf(qs[d], kr[d], a);
            sc = a;
        }
        s[j] = sc;
    }
    __syncthreads();
    // block max
    float lm = fmaxf(fmaxf(s[t], s[t+256]), fmaxf(s[t+512], s[t+768]));
    red[t] = lm;
    __syncthreads();
    for (int w = 128; w > 0; w >>= 1) { if (t < w) red[t] = fmaxf(red[t], red[t+w]); __syncthreads(); }
    const float m = red[0];
    __syncthreads();
    // exp + block sum
    float lsum = 0.f;
    for (int j = t; j < 1024; j += 256) {
        float p = expf(s[j] - m);   // masked entries: exp(-inf - m) = 0
        s[j] = p;
        lsum += p;
    }
    red[t] = lsum;
    __syncthreads();
    for (int w = 128; w > 0; w >>= 1) { if (t < w) red[t] += red[t+w]; __syncthreads(); }
    const float inv = 1.f / red[0];
    __syncthreads();
    // PV: wave w handles j = lo+w, lo+w+4, ...; lane d = output dim (coalesced V reads)
    const int d = t & 63, part = t >> 6;
    float acc = 0.f;
    for (int j = lo + part; j <= hi; j += 4) acc = fmaf(s[j], vp[(size_t)j*64 + d], acc);
    red[t] = acc;
    __syncthreads();
    if (t < 64) {
        const float o = (red[t] + red[t+64] + red[t+128] + red[t+192]) * inv;
        // merge is head-SLOW: out col = h*64 + d
        AO[((size_t)(b*NTOK + i))*PL + h*64 + t] = o;
    }
}

// ---------------------------------------------------------------------------
// Fused residual-add + LayerNorm (+ optional sigmoid). One wave per row.
// ---------------------------------------------------------------------------
template<int SIG>
__global__ __launch_bounds__(256) void add_ln(const float* __restrict__ X,
    const float* __restrict__ A, const float* __restrict__ g, const float* __restrict__ be,
    float* __restrict__ Out)
{
    const int row = blockIdx.x*4 + (threadIdx.x >> 6);
    const int lane = threadIdx.x & 63;
    const float* xr = X + (size_t)row*PL;
    const float* ar = A + (size_t)row*PL;
    float v[8];
    float sum = 0.f;
    #pragma unroll
    for (int u = 0; u < 8; u++) { v[u] = xr[lane + u*64] + ar[lane + u*64]; sum += v[u]; }
    #pragma unroll
    for (int o = 32; o > 0; o >>= 1) sum += __shfl_xor(sum, o);
    const float mu = sum * (1.f/512.f);
    float s2 = 0.f;
    #pragma unroll
    for (int u = 0; u < 8; u++) { float dd = v[u]-mu; s2 = fmaf(dd,dd,s2); }
    #pragma unroll
    for (int o = 32; o > 0; o >>= 1) s2 += __shfl_xor(s2, o);
    const float rstd = rsqrtf(s2*(1.f/512.f) + 1e-5f);
    #pragma unroll
    for (int u = 0; u < 8; u++) {
        const int c = lane + u*64;
        float y = (v[u]-mu)*rstd*g[c] + be[c];
        if (SIG) y = 1.f/(1.f + expf(-y));
        Out[(size_t)row*PL + c] = y;
    }
}

// ---------------------------------------------------------------------------
// FF GEMM: A[4096,512] @ B[512,512] + bias, optional exact GELU epilogue.
// ---------------------------------------------------------------------------
template<int GELU>
__global__ __launch_bounds__(256) void sgemm_bias(const float* __restrict__ A,
    const float* __restrict__ B, const float* __restrict__ bias, float* __restrict__ C)
{
    __shared__ float As[16][64];
    __shared__ float Bs[16][64];
    const int tid = threadIdx.x;
    const int tx = tid & 15, ty = tid >> 4;
    const int bm = blockIdx.x, bn = blockIdx.y;
    const int ar = tid >> 2, ac4 = (tid & 3) * 4;
    const int br = tid >> 4, bc4 = (tid & 15) * 4;
    float acc[4][4] = {};
    for (int kt = 0; kt < 512; kt += 16) {
        float4 av = *(const float4*)&A[(size_t)(bm*64 + ar)*512 + kt + ac4];
        float4 bv = *(const float4*)&B[(size_t)(kt + br)*512 + bn*64 + bc4];
        As[ac4+0][ar]=av.x; As[ac4+1][ar]=av.y; As[ac4+2][ar]=av.z; As[ac4+3][ar]=av.w;
        *(float4*)&Bs[br][bc4] = bv;
        __syncthreads();
        #pragma unroll
        for (int kk = 0; kk < 16; kk++) {
            float4 a4 = *(const float4*)&As[kk][ty*4];
            float4 b4 = *(const float4*)&Bs[kk][tx*4];
            float aa[4] = {a4.x,a4.y,a4.z,a4.w};
            float bb[4] = {b4.x,b4.y,b4.z,b4.w};
            #pragma unroll
            for (int ii=0; ii<4; ii++)
                #pragma unroll
                for (int jj=0; jj<4; jj++) acc[ii][jj] = fmaf(aa[ii], bb[jj], acc[ii][jj]);
        }
        __syncthreads();
    }
    #pragma unroll
    for (int ii=0; ii<4; ii++) {
        const int r = bm*64 + ty*4 + ii;
        #pragma unroll
        for (int jj=0; jj<4; jj++) {
            const int c = bn*64 + tx*4 + jj;
            float val = acc[ii][jj] + bias[c];
            if (GELU) val = 0.5f*val*(1.f + erff(val*0.70710678118654752f));
            C[(size_t)r*512 + c] = val;
        }
    }
}

// ---------------------------------------------------------------------------
// sim GEMM: per batch b, C[i,j] = dot(td1[b,i,:], td2[b,j,:]) / 512
// ---------------------------------------------------------------------------
__global__ __launch_bounds__(256) void sim_gemm(const float* __restrict__ TD1,
    const float* __restrict__ TD2, float* __restrict__ Out)
{
    const int b = blockIdx.z;
    const float* A  = TD1 + (size_t)b*NTOK*PL;
    const float* Bt = TD2 + (size_t)b*NTOK*PL;
    __shared__ float As[16][64];
    __shared__ float Bs[16][64];
    const int tid = threadIdx.x;
    const int tx = tid & 15, ty = tid >> 4;
    const int bm = blockIdx.x, bn = blockIdx.y;
    const int ar = tid >> 2, ac4 = (tid & 3) * 4;
    float acc[4][4] = {};
    for (int kt = 0; kt < 512; kt += 16) {
        float4 av = *(const float4*)&A [(size_t)(bm*64 + ar)*512 + kt + ac4];
        float4 bv = *(const float4*)&Bt[(size_t)(bn*64 + ar)*512 + kt + ac4];
        As[ac4+0][ar]=av.x; As[ac4+1][ar]=av.y; As[ac4+2][ar]=av.z; As[ac4+3][ar]=av.w;
        Bs[ac4+0][ar]=bv.x; Bs[ac4+1][ar]=bv.y; Bs[ac4+2][ar]=bv.z; Bs[ac4+3][ar]=bv.w;
        __syncthreads();
        #pragma unroll
        for (int kk = 0; kk < 16; kk++) {
            float4 a4 = *(const float4*)&As[kk][ty*4];
            float4 b4 = *(const float4*)&Bs[kk][tx*4];
            float aa[4] = {a4.x,a4.y,a4.z,a4.w};
            float bb[4] = {b4.x,b4.y,b4.z,b4.w};
            #pragma unroll
            for (int ii=0; ii<4; ii++)
                #pragma unroll
                for (int jj=0; jj<4; jj++) acc[ii][jj] = fmaf(aa[ii], bb[jj], acc[ii][jj]);
        }
        __syncthreads();
    }
    #pragma unroll
    for (int ii=0; ii<4; ii++)
        #pragma unroll
        for (int jj=0; jj<4; jj++)
            Out[((size_t)b*NTOK + bm*64 + ty*4 + ii)*NTOK + bn*64 + tx*4 + jj] =
                acc[ii][jj] * (1.f/512.f);
}

// ---------------------------------------------------------------------------
extern "C" void kernel_launch(void* const* d_in, const int* in_sizes, int n_in,
                              void* d_out, int out_size, void* d_ws, size_t ws_size,
                              hipStream_t stream)
{
    const float* x = (const float*)d_in[0];
    const float* wqkv[2] = {(const float*)d_in[1],  (const float*)d_in[11]};
    const float* bqkv[2] = {(const float*)d_in[2],  (const float*)d_in[12]};
    const float* ga[2]   = {(const float*)d_in[3],  (const float*)d_in[13]};
    const float* bea[2]  = {(const float*)d_in[4],  (const float*)d_in[14]};
    const float* w1[2]   = {(const float*)d_in[5],  (const float*)d_in[15]};
    const float* b1[2]   = {(const float*)d_in[6],  (const float*)d_in[16]};
    const float* w2[2]   = {(const float*)d_in[7],  (const float*)d_in[17]};
    const float* b2[2]   = {(const float*)d_in[8],  (const float*)d_in[18]};
    const float* gb[2]   = {(const float*)d_in[9],  (const float*)d_in[19]};
    const float* beb[2]  = {(const float*)d_in[10], (const float*)d_in[20]};

    const size_t R = (size_t)ROWS * PL;   // 2,097,152 floats = 8 MB
    float* ws  = (float*)d_ws;            // needs 5*R*4 = 40 MB
    float* Qb  = ws;                      // also reused as FF output
    float* AO  = ws + R;                  // attn out, reused as gelu hidden
    float* X1  = ws + 2*R;
    float* TD1 = ws + 3*R;
    float* TD2 = ws + 4*R;
    float* out = (float*)d_out;
    float* Kb  = out;                     // K,V live in d_out (2*R floats = out_size)
    float* Vb  = out + R;                 // overwritten by sim at the very end

    for (int L = 0; L < 2; L++) {
        float* TD = (L == 0) ? TD1 : TD2;
        qkv_gemm<<<dim3(64, 24), 256, 0, stream>>>(x, wqkv[L], bqkv[L], Qb, Kb, Vb);
        if (L == 0) attn_kernel<1><<<32768, 256, 0, stream>>>(Qb, Kb, Vb, AO);
        else        attn_kernel<0><<<32768, 256, 0, stream>>>(Qb, Kb, Vb, AO);
        add_ln<0><<<1024, 256, 0, stream>>>(x, AO, ga[L], bea[L], X1);
        sgemm_bias<1><<<dim3(64, 8), 256, 0, stream>>>(X1, w1[L], b1[L], AO);   // gelu hidden
        sgemm_bias<0><<<dim3(64, 8), 256, 0, stream>>>(AO, w2[L], b2[L], Qb);   // ff out
        add_ln<1><<<1024, 256, 0, stream>>>(X1, Qb, gb[L], beb[L], TD);         // sigmoid(LN)
    }
    sim_gemm<<<dim3(16, 16, 4), 256, 0, stream>>>(TD1, TD2, out);
}

// Round 2
// 701.609 us; speedup vs baseline: 3.2494x; 3.2494x over previous
//
#include <hip/hip_runtime.h>
#include <hip/hip_bf16.h>
#include <math.h>

// Problem constants
#define NTOK   1024
#define PL     512
#define NHEAD  8
#define DHEAD  64
#define BATCH  4
#define ROWS   (BATCH*NTOK)          // 4096
#define QSCALE 0.04419417382415922f  // 1/sqrt(512)

// ---------------------------------------------------------------------------
// qkv GEMM: X[4096,512] @ W[512,1536] + bias -> scatter to Q,K,V [B,H,N,64]
// head split is head-FAST: col c (within a 512 third): d = c>>3, h = c&7
// ---------------------------------------------------------------------------
__global__ __launch_bounds__(256) void qkv_gemm(const float* __restrict__ X,
    const float* __restrict__ W, const float* __restrict__ bias,
    float* __restrict__ Q, float* __restrict__ Kb, float* __restrict__ Vb)
{
    __shared__ float As[16][64];
    __shared__ float Bs[16][64];
    const int tid = threadIdx.x;
    const int tx = tid & 15, ty = tid >> 4;
    const int bm = blockIdx.x, bn = blockIdx.y;
    const int ar = tid >> 2, ac4 = (tid & 3) * 4;
    const int br = tid >> 4, bc4 = (tid & 15) * 4;
    float acc[4][4] = {};
    for (int kt = 0; kt < 512; kt += 16) {
        float4 av = *(const float4*)&X[(size_t)(bm*64 + ar)*512 + kt + ac4];
        float4 bv = *(const float4*)&W[(size_t)(kt + br)*1536 + bn*64 + bc4];
        As[ac4+0][ar]=av.x; As[ac4+1][ar]=av.y; As[ac4+2][ar]=av.z; As[ac4+3][ar]=av.w;
        *(float4*)&Bs[br][bc4] = bv;
        __syncthreads();
        #pragma unroll
        for (int kk = 0; kk < 16; kk++) {
            float4 a4 = *(const float4*)&As[kk][ty*4];
            float4 b4 = *(const float4*)&Bs[kk][tx*4];
            float aa[4] = {a4.x,a4.y,a4.z,a4.w};
            float bb[4] = {b4.x,b4.y,b4.z,b4.w};
            #pragma unroll
            for (int ii=0; ii<4; ii++)
                #pragma unroll
                for (int jj=0; jj<4; jj++) acc[ii][jj] = fmaf(aa[ii], bb[jj], acc[ii][jj]);
        }
        __syncthreads();
    }
    #pragma unroll
    for (int ii=0; ii<4; ii++) {
        const int r = bm*64 + ty*4 + ii;
        const int b = r >> 10, n = r & 1023;
        #pragma unroll
        for (int jj=0; jj<4; jj++) {
            const int c = bn*64 + tx*4 + jj;
            float v = acc[ii][jj] + bias[c];
            const int part = c >> 9;       // 0=q 1=k 2=v (uniform per block)
            const int c2 = c & 511;
            const int h = c2 & 7, d = c2 >> 3;
            const int idx = (((b*NHEAD + h)*NTOK) + n)*DHEAD + d;
            if      (part == 0) Q[idx]  = v * QSCALE;
            else if (part == 1) Kb[idx] = v;
            else                Vb[idx] = v;
        }
    }
}

// ---------------------------------------------------------------------------
// Tiled flash attention, fp32 VALU. Block = 256 thr, one (b,h, 64-query tile).
// K tile LDS layout: chunk-XOR swizzle so stride-256B column reads are
// conflict-free:  Ks[c][ ((d>>2) ^ (c>>2)) * 4 + (d&3) ]
// V tile transposed with the same swizzle: Vt[dim][ ((j>>2)^(dim>>2))*4 + (j&3) ]
// Q and P tiles: stride 68 (16B-aligned pad) -> stage writes & frag reads clean.
// ---------------------------------------------------------------------------
template<int CAUSAL>
__global__ __launch_bounds__(256) void attn_tile(const float* __restrict__ Qg,
    const float* __restrict__ Kg, const float* __restrict__ Vg, float* __restrict__ AO)
{
    __shared__ float Qs[64][68];
    __shared__ float Ks[64][64];
    __shared__ float Vt[64][64];
    __shared__ float Ps[64][68];

    const int tid = threadIdx.x;
    const int tx = tid & 15, ty = tid >> 4;
    const int tx4 = tx*4, ty4 = ty*4;
    const int bh = blockIdx.x;                              // 0..31
    const int qt = CAUSAL ? (15 - (int)blockIdx.y) : (int)blockIdx.y;  // long jobs first
    const int b = bh >> 3, h = bh & 7;
    const float* qb = Qg + (size_t)bh * (NTOK*DHEAD);
    const float* kb = Kg + (size_t)bh * (NTOK*DHEAD);
    const float* vb = Vg + (size_t)bh * (NTOK*DHEAD);

    // ---- stage Q tile (reused across all k-tiles) ----
    {
        const int r = tid >> 2, c0 = (tid & 3) * 16;
        const float* src = &qb[(size_t)(qt*64 + r)*64 + c0];
        #pragma unroll
        for (int u = 0; u < 4; u++)
            *(float4*)&Qs[r][c0 + u*4] = *(const float4*)&src[u*4];
    }

    float m_[4], l_[4], accO[4][4];
    #pragma unroll
    for (int ii=0;ii<4;ii++){ m_[ii] = -INFINITY; l_[ii] = 0.f;
        #pragma unroll
        for (int jj=0;jj<4;jj++) accO[ii][jj] = 0.f; }

    const int kt0 = CAUSAL ? 0 : qt;
    const int kt1 = CAUSAL ? qt : 15;

    for (int kt = kt0; kt <= kt1; kt++) {
        __syncthreads();   // protect Ks/Vt/Ps from previous iteration's readers
        // ---- stage K, V tiles ----
        {
            const int r = tid >> 2;                 // key row within tile
            const int key = r >> 2;                 // XOR key
            const float* ksrc = &kb[(size_t)(kt*64 + r)*64 + (tid&3)*16];
            const float* vsrc = &vb[(size_t)(kt*64 + r)*64 + (tid&3)*16];
            #pragma unroll
            for (int u = 0; u < 4; u++) {
                const int ch = (tid&3)*4 + u;       // d>>2 chunk index
                float4 kv = *(const float4*)&ksrc[u*4];
                *(float4*)&Ks[r][(ch ^ key) << 2] = kv;
                float4 vv = *(const float4*)&vsrc[u*4];
                const float vval[4] = {vv.x, vv.y, vv.z, vv.w};
                #pragma unroll
                for (int e = 0; e < 4; e++) {
                    const int dim = (ch << 2) + e;
                    Vt[dim][((key ^ (dim>>2)) << 2) + (r & 3)] = vval[e];
                }
            }
        }
        __syncthreads();
        // ---- S = Q K^T (4x4 per thread) ----
        float s[4][4];
        #pragma unroll
        for (int ii=0;ii<4;ii++)
            #pragma unroll
            for (int jj=0;jj<4;jj++) s[ii][jj]=0.f;
        #pragma unroll
        for (int d0 = 0; d0 < 64; d0 += 4) {
            float4 a[4], bk[4];
            #pragma unroll
            for (int ii=0;ii<4;ii++) a[ii] = *(const float4*)&Qs[ty4+ii][d0];
            const int koff = (((d0>>2) ^ tx) << 2);
            #pragma unroll
            for (int jj=0;jj<4;jj++) bk[jj] = *(const float4*)&Ks[tx4+jj][koff];
            #pragma unroll
            for (int ii=0;ii<4;ii++)
                #pragma unroll
                for (int jj=0;jj<4;jj++) {
                    s[ii][jj] = fmaf(a[ii].x, bk[jj].x, s[ii][jj]);
                    s[ii][jj] = fmaf(a[ii].y, bk[jj].y, s[ii][jj]);
                    s[ii][jj] = fmaf(a[ii].z, bk[jj].z, s[ii][jj]);
                    s[ii][jj] = fmaf(a[ii].w, bk[jj].w, s[ii][jj]);
                }
        }
        // ---- mask (diagonal tile only) ----
        if (kt == qt) {
            #pragma unroll
            for (int ii=0;ii<4;ii++) {
                const int ig = qt*64 + ty4 + ii;
                #pragma unroll
                for (int jj=0;jj<4;jj++) {
                    const int jg = kt*64 + tx4 + jj;
                    if (CAUSAL ? (jg > ig) : (jg < ig)) s[ii][jj] = -INFINITY;
                }
            }
        }
        // ---- online softmax update, write P ----
        #pragma unroll
        for (int ii=0;ii<4;ii++) {
            float rm = fmaxf(fmaxf(s[ii][0],s[ii][1]), fmaxf(s[ii][2],s[ii][3]));
            #pragma unroll
            for (int off=1; off<16; off<<=1) rm = fmaxf(rm, __shfl_xor(rm, off));
            const float mnew = fmaxf(m_[ii], rm);
            const float scale = __expf(m_[ii] - mnew);   // -inf - finite -> 0
            float ps = 0.f;
            #pragma unroll
            for (int jj=0;jj<4;jj++) { float p = __expf(s[ii][jj] - mnew); s[ii][jj] = p; ps += p; }
            #pragma unroll
            for (int off=1; off<16; off<<=1) ps += __shfl_xor(ps, off);
            l_[ii] = l_[ii]*scale + ps;
            m_[ii] = mnew;
            #pragma unroll
            for (int jj=0;jj<4;jj++) accO[ii][jj] *= scale;
            *(float4*)&Ps[ty4+ii][tx4] = *(float4*)&s[ii][0];
        }
        __syncthreads();
        // ---- O += P V ----
        #pragma unroll
        for (int j0 = 0; j0 < 64; j0 += 4) {
            float4 p[4], v[4];
            #pragma unroll
            for (int ii=0;ii<4;ii++) p[ii] = *(const float4*)&Ps[ty4+ii][j0];
            const int voff = (((j0>>2) ^ tx) << 2);
            #pragma unroll
            for (int jj=0;jj<4;jj++) v[jj] = *(const float4*)&Vt[tx4+jj][voff];
            #pragma unroll
            for (int ii=0;ii<4;ii++)
                #pragma unroll
                for (int jj=0;jj<4;jj++) {
                    accO[ii][jj] = fmaf(p[ii].x, v[jj].x, accO[ii][jj]);
                    accO[ii][jj] = fmaf(p[ii].y, v[jj].y, accO[ii][jj]);
                    accO[ii][jj] = fmaf(p[ii].z, v[jj].z, accO[ii][jj]);
                    accO[ii][jj] = fmaf(p[ii].w, v[jj].w, accO[ii][jj]);
                }
        }
    }
    // ---- epilogue: divide by l, write head-SLOW merged output ----
    #pragma unroll
    for (int ii=0;ii<4;ii++) {
        const float inv = 1.f / l_[ii];
        float4 o;
        o.x = accO[ii][0]*inv; o.y = accO[ii][1]*inv;
        o.z = accO[ii][2]*inv; o.w = accO[ii][3]*inv;
        *(float4*)&AO[((size_t)(b*NTOK + qt*64 + ty4 + ii))*PL + h*64 + tx4] = o;
    }
}

// ---------------------------------------------------------------------------
// Fused residual-add + LayerNorm (+ optional sigmoid). One wave per row.
// ---------------------------------------------------------------------------
template<int SIG>
__global__ __launch_bounds__(256) void add_ln(const float* __restrict__ X,
    const float* __restrict__ A, const float* __restrict__ g, const float* __restrict__ be,
    float* __restrict__ Out)
{
    const int row = blockIdx.x*4 + (threadIdx.x >> 6);
    const int lane = threadIdx.x & 63;
    const float* xr = X + (size_t)row*PL;
    const float* ar = A + (size_t)row*PL;
    float v[8];
    float sum = 0.f;
    #pragma unroll
    for (int u = 0; u < 8; u++) { v[u] = xr[lane + u*64] + ar[lane + u*64]; sum += v[u]; }
    #pragma unroll
    for (int o = 32; o > 0; o >>= 1) sum += __shfl_xor(sum, o);
    const float mu = sum * (1.f/512.f);
    float s2 = 0.f;
    #pragma unroll
    for (int u = 0; u < 8; u++) { float dd = v[u]-mu; s2 = fmaf(dd,dd,s2); }
    #pragma unroll
    for (int o = 32; o > 0; o >>= 1) s2 += __shfl_xor(s2, o);
    const float rstd = rsqrtf(s2*(1.f/512.f) + 1e-5f);
    #pragma unroll
    for (int u = 0; u < 8; u++) {
        const int c = lane + u*64;
        float y = (v[u]-mu)*rstd*g[c] + be[c];
        if (SIG) y = 1.f/(1.f + expf(-y));
        Out[(size_t)row*PL + c] = y;
    }
}

// ---------------------------------------------------------------------------
// FF GEMM: A[4096,512] @ B[512,512] + bias, optional exact GELU epilogue.
// ---------------------------------------------------------------------------
template<int GELU>
__global__ __launch_bounds__(256) void sgemm_bias(const float* __restrict__ A,
    const float* __restrict__ B, const float* __restrict__ bias, float* __restrict__ C)
{
    __shared__ float As[16][64];
    __shared__ float Bs[16][64];
    const int tid = threadIdx.x;
    const int tx = tid & 15, ty = tid >> 4;
    const int bm = blockIdx.x, bn = blockIdx.y;
    const int ar = tid >> 2, ac4 = (tid & 3) * 4;
    const int br = tid >> 4, bc4 = (tid & 15) * 4;
    float acc[4][4] = {};
    for (int kt = 0; kt < 512; kt += 16) {
        float4 av = *(const float4*)&A[(size_t)(bm*64 + ar)*512 + kt + ac4];
        float4 bv = *(const float4*)&B[(size_t)(kt + br)*512 + bn*64 + bc4];
        As[ac4+0][ar]=av.x; As[ac4+1][ar]=av.y; As[ac4+2][ar]=av.z; As[ac4+3][ar]=av.w;
        *(float4*)&Bs[br][bc4] = bv;
        __syncthreads();
        #pragma unroll
        for (int kk = 0; kk < 16; kk++) {
            float4 a4 = *(const float4*)&As[kk][ty*4];
            float4 b4 = *(const float4*)&Bs[kk][tx*4];
            float aa[4] = {a4.x,a4.y,a4.z,a4.w};
            float bb[4] = {b4.x,b4.y,b4.z,b4.w};
            #pragma unroll
            for (int ii=0; ii<4; ii++)
                #pragma unroll
                for (int jj=0; jj<4; jj++) acc[ii][jj] = fmaf(aa[ii], bb[jj], acc[ii][jj]);
        }
        __syncthreads();
    }
    #pragma unroll
    for (int ii=0; ii<4; ii++) {
        const int r = bm*64 + ty*4 + ii;
        #pragma unroll
        for (int jj=0; jj<4; jj++) {
            const int c = bn*64 + tx*4 + jj;
            float val = acc[ii][jj] + bias[c];
            if (GELU) val = 0.5f*val*(1.f + erff(val*0.70710678118654752f));
            C[(size_t)r*512 + c] = val;
        }
    }
}

// ---------------------------------------------------------------------------
// sim GEMM: per batch b, C[i,j] = dot(td1[b,i,:], td2[b,j,:]) / 512
// ---------------------------------------------------------------------------
__global__ __launch_bounds__(256) void sim_gemm(const float* __restrict__ TD1,
    const float* __restrict__ TD2, float* __restrict__ Out)
{
    const int b = blockIdx.z;
    const float* A  = TD1 + (size_t)b*NTOK*PL;
    const float* Bt = TD2 + (size_t)b*NTOK*PL;
    __shared__ float As[16][64];
    __shared__ float Bs[16][64];
    const int tid = threadIdx.x;
    const int tx = tid & 15, ty = tid >> 4;
    const int bm = blockIdx.x, bn = blockIdx.y;
    const int ar = tid >> 2, ac4 = (tid & 3) * 4;
    float acc[4][4] = {};
    for (int kt = 0; kt < 512; kt += 16) {
        float4 av = *(const float4*)&A [(size_t)(bm*64 + ar)*512 + kt + ac4];
        float4 bv = *(const float4*)&Bt[(size_t)(bn*64 + ar)*512 + kt + ac4];
        As[ac4+0][ar]=av.x; As[ac4+1][ar]=av.y; As[ac4+2][ar]=av.z; As[ac4+3][ar]=av.w;
        Bs[ac4+0][ar]=bv.x; Bs[ac4+1][ar]=bv.y; Bs[ac4+2][ar]=bv.z; Bs[ac4+3][ar]=bv.w;
        __syncthreads();
        #pragma unroll
        for (int kk = 0; kk < 16; kk++) {
            float4 a4 = *(const float4*)&As[kk][ty*4];
            float4 b4 = *(const float4*)&Bs[kk][tx*4];
            float aa[4] = {a4.x,a4.y,a4.z,a4.w};
            float bb[4] = {b4.x,b4.y,b4.z,b4.w};
            #pragma unroll
            for (int ii=0; ii<4; ii++)
                #pragma unroll
                for (int jj=0; jj<4; jj++) acc[ii][jj] = fmaf(aa[ii], bb[jj], acc[ii][jj]);
        }
        __syncthreads();
    }
    #pragma unroll
    for (int ii=0; ii<4; ii++)
        #pragma unroll
        for (int jj=0; jj<4; jj++)
            Out[((size_t)b*NTOK + bm*64 + ty*4 + ii)*NTOK + bn*64 + tx*4 + jj] =
                acc[ii][jj] * (1.f/512.f);
}

// ---------------------------------------------------------------------------
extern "C" void kernel_launch(void* const* d_in, const int* in_sizes, int n_in,
                              void* d_out, int out_size, void* d_ws, size_t ws_size,
                              hipStream_t stream)
{
    const float* x = (const float*)d_in[0];
    const float* wqkv[2] = {(const float*)d_in[1],  (const float*)d_in[11]};
    const float* bqkv[2] = {(const float*)d_in[2],  (const float*)d_in[12]};
    const float* ga[2]   = {(const float*)d_in[3],  (const float*)d_in[13]};
    const float* bea[2]  = {(const float*)d_in[4],  (const float*)d_in[14]};
    const float* w1[2]   = {(const float*)d_in[5],  (const float*)d_in[15]};
    const float* b1[2]   = {(const float*)d_in[6],  (const float*)d_in[16]};
    const float* w2[2]   = {(const float*)d_in[7],  (const float*)d_in[17]};
    const float* b2[2]   = {(const float*)d_in[8],  (const float*)d_in[18]};
    const float* gb[2]   = {(const float*)d_in[9],  (const float*)d_in[19]};
    const float* beb[2]  = {(const float*)d_in[10], (const float*)d_in[20]};

    const size_t R = (size_t)ROWS * PL;   // 2,097,152 floats = 8 MB
    float* ws  = (float*)d_ws;            // needs 5*R*4 = 40 MB
    float* Qb  = ws;                      // also reused as FF output
    float* AO  = ws + R;                  // attn out, reused as gelu hidden
    float* X1  = ws + 2*R;
    float* TD1 = ws + 3*R;
    float* TD2 = ws + 4*R;
    float* out = (float*)d_out;
    float* Kb  = out;                     // K,V live in d_out (2*R floats = out_size)
    float* Vb  = out + R;                 // overwritten by sim at the very end

    for (int L = 0; L < 2; L++) {
        float* TD = (L == 0) ? TD1 : TD2;
        qkv_gemm<<<dim3(64, 24), 256, 0, stream>>>(x, wqkv[L], bqkv[L], Qb, Kb, Vb);
        if (L == 0) attn_tile<1><<<dim3(32, 16), 256, 0, stream>>>(Qb, Kb, Vb, AO);
        else        attn_tile<0><<<dim3(32, 16), 256, 0, stream>>>(Qb, Kb, Vb, AO);
        add_ln<0><<<1024, 256, 0, stream>>>(x, AO, ga[L], bea[L], X1);
        sgemm_bias<1><<<dim3(64, 8), 256, 0, stream>>>(X1, w1[L], b1[L], AO);   // gelu hidden
        sgemm_bias<0><<<dim3(64, 8), 256, 0, stream>>>(AO, w2[L], b2[L], Qb);   // ff out
        add_ln<1><<<1024, 256, 0, stream>>>(X1, Qb, gb[L], beb[L], TD);         // sigmoid(LN)
    }
    sim_gemm<<<dim3(16, 16, 4), 256, 0, stream>>>(TD1, TD2, out);
}

// Round 3
// 297.979 us; speedup vs baseline: 7.6510x; 2.3546x over previous
//
#include <hip/hip_runtime.h>
#include <math.h>

// ---------------------------------------------------------------------------
// bf16-MFMA implementation.
//  - dense GEMMs (qkv, ff1, ff2): split-bf16 (hi/lo) 3-term MFMA => ~fp32 accuracy
//  - attention + sim: plain bf16 MFMA
//  - mfma_f32_16x16x32_bf16 layouts: A: lane l holds A[l&15][8*(l>>4)+j];
//    B: lane l holds B[8*(l>>4)+j][l&15];  C/D: col=l&15, row=(l>>4)*4+reg
// ---------------------------------------------------------------------------

typedef float f32x4 __attribute__((ext_vector_type(4)));
typedef short s16x8 __attribute__((ext_vector_type(8)));
typedef unsigned short u16;

#define NTOK 1024
#define PL 512
#define QSCALE 0.04419417382415922f  // 1/sqrt(512)

__device__ inline u16 f2bf(float f) {
    unsigned u = __builtin_bit_cast(unsigned, f);
    unsigned r = u + 0x7fffu + ((u >> 16) & 1u);   // RNE
    return (u16)(r >> 16);
}
__device__ inline float bf2f(u16 h) {
    unsigned u = ((unsigned)h) << 16;
    return __builtin_bit_cast(float, u);
}

// ---------------------------------------------------------------------------
// x -> hi/lo bf16 split (elementwise)
// ---------------------------------------------------------------------------
__global__ __launch_bounds__(256) void convert_x(const float* __restrict__ X,
    u16* __restrict__ hi, u16* __restrict__ lo)
{
    const int i = (blockIdx.x * 256 + threadIdx.x) * 4;
    float4 v = *(const float4*)&X[i];
    float vv[4] = {v.x, v.y, v.z, v.w};
    #pragma unroll
    for (int j = 0; j < 4; j++) {
        u16 h = f2bf(vv[j]);
        hi[i + j] = h;
        lo[i + j] = f2bf(vv[j] - bf2f(h));
    }
}

// ---------------------------------------------------------------------------
// W [512][N] f32 -> Wt [N][512] bf16 hi/lo (tiled transpose)
// ---------------------------------------------------------------------------
__global__ __launch_bounds__(256) void convert_wt(const float* __restrict__ W,
    u16* __restrict__ Whi, u16* __restrict__ Wlo, const int N)
{
    __shared__ float T[32][36];
    const int k0 = blockIdx.x * 32, n0 = blockIdx.y * 32;
    const int tr = threadIdx.x >> 3, tc = (threadIdx.x & 7) * 4;
    *(float4*)&T[tr][tc] = *(const float4*)&W[(size_t)(k0 + tr) * N + n0 + tc];
    __syncthreads();
    u16 hv[4], lv[4];
    #pragma unroll
    for (int j = 0; j < 4; j++) {
        float v = T[tc + j][tr];
        hv[j] = f2bf(v);
        lv[j] = f2bf(v - bf2f(hv[j]));
    }
    const size_t o = (size_t)(n0 + tr) * 512 + k0 + tc;
    #pragma unroll
    for (int j = 0; j < 4; j++) { Whi[o + j] = hv[j]; Wlo[o + j] = lv[j]; }
}

// ---------------------------------------------------------------------------
// Split-bf16 MFMA GEMM: A[4096][512] (hi/lo) x Bt[N][512] (hi/lo) + bias
// EPI: 0 = qkv scatter (Q scaled, K, Vt transposed), 1 = gelu -> hi/lo,
//      2 = f32 out. Block 256 thr = 4 waves (2x2), BN=128, BK=64.
// LDS chunk-XOR swizzle (ch ^ (row&7)) on both write and read sides.
// ---------------------------------------------------------------------------
template<int BM, int EPI>
__global__ __launch_bounds__(256) void gemm_split(
    const u16* __restrict__ Ahi, const u16* __restrict__ Alo,
    const u16* __restrict__ Bhi, const u16* __restrict__ Blo,
    const float* __restrict__ bias, const int Ncols,
    float* __restrict__ outF, u16* __restrict__ o1, u16* __restrict__ o2,
    u16* __restrict__ o3)
{
    constexpr int FM = BM / 32;
    __shared__ u16 Ah[BM * 64], Al[BM * 64], Bh[128 * 64], Bl[128 * 64];
    const int t = threadIdx.x, l = t & 63, w = t >> 6;
    const int lr = l & 15, lg = l >> 4;
    const int wm = w >> 1, wn = w & 1;
    const int m0 = blockIdx.x * BM, n0 = blockIdx.y * 128;

    f32x4 acc[FM][4];
    #pragma unroll
    for (int i = 0; i < FM; i++)
        #pragma unroll
        for (int j = 0; j < 4; j++) acc[i][j] = f32x4{0.f, 0.f, 0.f, 0.f};

    const int sr = t >> 3, sc = t & 7;
    for (int k0 = 0; k0 < 512; k0 += 64) {
        __syncthreads();
        #pragma unroll
        for (int q = 0; q < BM / 32; q++) {
            const int r = sr + 32 * q;
            const int d = r * 64 + ((sc ^ (r & 7)) << 3);
            const size_t g = (size_t)(m0 + r) * 512 + k0 + sc * 8;
            *(s16x8*)&Ah[d] = *(const s16x8*)&Ahi[g];
            *(s16x8*)&Al[d] = *(const s16x8*)&Alo[g];
        }
        #pragma unroll
        for (int q = 0; q < 4; q++) {
            const int r = sr + 32 * q;
            const int d = r * 64 + ((sc ^ (r & 7)) << 3);
            const size_t g = (size_t)(n0 + r) * 512 + k0 + sc * 8;
            *(s16x8*)&Bh[d] = *(const s16x8*)&Bhi[g];
            *(s16x8*)&Bl[d] = *(const s16x8*)&Blo[g];
        }
        __syncthreads();
        #pragma unroll
        for (int kk = 0; kk < 2; kk++) {
            s16x8 ah[FM], al[FM], bh[4], bl[4];
            const int ch = kk * 4 + lg;
            #pragma unroll
            for (int fm = 0; fm < FM; fm++) {
                const int r = wm * (BM / 2) + fm * 16 + lr;
                const int d = r * 64 + ((ch ^ (r & 7)) << 3);
                ah[fm] = *(const s16x8*)&Ah[d];
                al[fm] = *(const s16x8*)&Al[d];
            }
            #pragma unroll
            for (int fn = 0; fn < 4; fn++) {
                const int r = wn * 64 + fn * 16 + lr;
                const int d = r * 64 + ((ch ^ (r & 7)) << 3);
                bh[fn] = *(const s16x8*)&Bh[d];
                bl[fn] = *(const s16x8*)&Bl[d];
            }
            #pragma unroll
            for (int fm = 0; fm < FM; fm++)
                #pragma unroll
                for (int fn = 0; fn < 4; fn++) {
                    acc[fm][fn] = __builtin_amdgcn_mfma_f32_16x16x32_bf16(ah[fm], bh[fn], acc[fm][fn], 0, 0, 0);
                    acc[fm][fn] = __builtin_amdgcn_mfma_f32_16x16x32_bf16(ah[fm], bl[fn], acc[fm][fn], 0, 0, 0);
                    acc[fm][fn] = __builtin_amdgcn_mfma_f32_16x16x32_bf16(al[fm], bh[fn], acc[fm][fn], 0, 0, 0);
                }
        }
    }
    // epilogue
    #pragma unroll
    for (int fm = 0; fm < FM; fm++)
        #pragma unroll
        for (int fn = 0; fn < 4; fn++)
            #pragma unroll
            for (int rg = 0; rg < 4; rg++) {
                const int r = m0 + wm * (BM / 2) + fm * 16 + lg * 4 + rg;
                const int c = n0 + wn * 64 + fn * 16 + lr;
                float v = acc[fm][fn][rg] + bias[c];
                if constexpr (EPI == 0) {
                    const int part = c >> 9, c2 = c & 511;
                    const int h = c2 & 7, dd = c2 >> 3;
                    const int b = r >> 10, n = r & 1023;
                    const size_t bh_ = (size_t)(b * 8 + h);
                    if (part == 0)      o1[(bh_ * 1024 + n) * 64 + dd] = f2bf(v * QSCALE);
                    else if (part == 1) o2[(bh_ * 1024 + n) * 64 + dd] = f2bf(v);
                    else                o3[(bh_ * 64 + dd) * 1024 + n] = f2bf(v);
                } else if constexpr (EPI == 1) {
                    float gl = 0.5f * v * (1.f + erff(v * 0.70710678118654752f));
                    u16 hv = f2bf(gl);
                    o1[(size_t)r * Ncols + c] = hv;
                    o2[(size_t)r * Ncols + c] = f2bf(gl - bf2f(hv));
                } else {
                    outF[(size_t)r * Ncols + c] = v;
                }
            }
}

// ---------------------------------------------------------------------------
// Flash attention, bf16 MFMA. Block = 256 thr = 4 waves; one (b,h, 64-q tile).
// Each wave owns 16 q rows; K/Vt frags read from global (L2-resident);
// P transposed through wave-private LDS (stride 72 -> 16B aligned, low conflict)
// ---------------------------------------------------------------------------
template<int CAUSAL>
__global__ __launch_bounds__(256) void attn_mfma(const u16* __restrict__ Qg,
    const u16* __restrict__ Kg, const u16* __restrict__ Vtg, float* __restrict__ AO)
{
    __shared__ u16 Ps[4][16 * 72];
    const int t = threadIdx.x, l = t & 63, w = t >> 6;
    const int lr = l & 15, lg = l >> 4;
    const int bh = blockIdx.x;
    const int b = bh >> 3, h = bh & 7;
    const int qt = CAUSAL ? (15 - (int)blockIdx.y) : (int)blockIdx.y;  // long jobs first
    const u16* Qb = Qg + (size_t)bh * (NTOK * 64);
    const u16* Kb = Kg + (size_t)bh * (NTOK * 64);
    const u16* Vb = Vtg + (size_t)bh * (64 * NTOK);
    const int q0 = qt * 64 + w * 16;

    s16x8 aq[2];
    aq[0] = *(const s16x8*)&Qb[(size_t)(q0 + lr) * 64 + lg * 8];
    aq[1] = *(const s16x8*)&Qb[(size_t)(q0 + lr) * 64 + 32 + lg * 8];

    f32x4 o[4];
    float m_[4], l_[4];
    #pragma unroll
    for (int f = 0; f < 4; f++) o[f] = f32x4{0.f, 0.f, 0.f, 0.f};
    #pragma unroll
    for (int r = 0; r < 4; r++) { m_[r] = -INFINITY; l_[r] = 0.f; }

    const int kt0 = CAUSAL ? 0 : qt, kt1 = CAUSAL ? qt : 15;
    for (int kt = kt0; kt <= kt1; kt++) {
        // ---- S = Q K^T ----
        f32x4 s[4];
        #pragma unroll
        for (int f = 0; f < 4; f++) s[f] = f32x4{0.f, 0.f, 0.f, 0.f};
        #pragma unroll
        for (int kk = 0; kk < 2; kk++)
            #pragma unroll
            for (int f = 0; f < 4; f++) {
                s16x8 bk = *(const s16x8*)&Kb[(size_t)(kt * 64 + f * 16 + lr) * 64 + kk * 32 + lg * 8];
                s[f] = __builtin_amdgcn_mfma_f32_16x16x32_bf16(aq[kk], bk, s[f], 0, 0, 0);
            }
        // ---- mask on diagonal tile ----
        if (kt == qt) {
            #pragma unroll
            for (int f = 0; f < 4; f++) {
                const int key = kt * 64 + f * 16 + lr;
                #pragma unroll
                for (int r = 0; r < 4; r++) {
                    const int q = q0 + lg * 4 + r;
                    if (CAUSAL ? (key > q) : (key < q)) s[f][r] = -INFINITY;
                }
            }
        }
        // ---- online softmax (per reg r = q-row) ----
        float scale[4];
        #pragma unroll
        for (int r = 0; r < 4; r++) {
            float rm = fmaxf(fmaxf(s[0][r], s[1][r]), fmaxf(s[2][r], s[3][r]));
            #pragma unroll
            for (int off = 1; off < 16; off <<= 1) rm = fmaxf(rm, __shfl_xor(rm, off));
            const float mn = fmaxf(m_[r], rm);
            scale[r] = __expf(m_[r] - mn);
            float ps = 0.f;
            #pragma unroll
            for (int f = 0; f < 4; f++) { float p = __expf(s[f][r] - mn); s[f][r] = p; ps += p; }
            #pragma unroll
            for (int off = 1; off < 16; off <<= 1) ps += __shfl_xor(ps, off);
            l_[r] = l_[r] * scale[r] + ps;
            m_[r] = mn;
        }
        // ---- P -> LDS (bf16), rescale O ----
        #pragma unroll
        for (int f = 0; f < 4; f++)
            #pragma unroll
            for (int r = 0; r < 4; r++)
                Ps[w][(lg * 4 + r) * 72 + f * 16 + lr] = f2bf(s[f][r]);
        #pragma unroll
        for (int f = 0; f < 4; f++)
            #pragma unroll
            for (int r = 0; r < 4; r++) o[f][r] *= scale[r];
        // ---- O += P V ----
        #pragma unroll
        for (int kk = 0; kk < 2; kk++) {
            s16x8 ap = *(const s16x8*)&Ps[w][lr * 72 + kk * 32 + lg * 8];
            #pragma unroll
            for (int f = 0; f < 4; f++) {
                s16x8 bv = *(const s16x8*)&Vb[(size_t)(f * 16 + lr) * NTOK + kt * 64 + kk * 32 + lg * 8];
                o[f] = __builtin_amdgcn_mfma_f32_16x16x32_bf16(ap, bv, o[f], 0, 0, 0);
            }
        }
    }
    // ---- epilogue: head-SLOW merge, f32 ----
    #pragma unroll
    for (int f = 0; f < 4; f++)
        #pragma unroll
        for (int r = 0; r < 4; r++)
            AO[(size_t)(b * NTOK + q0 + lg * 4 + r) * PL + h * 64 + f * 16 + lr] = o[f][r] / l_[r];
}

// ---------------------------------------------------------------------------
// add+LN variants. A: x(f32)+attn(f32) -> LN -> hi/lo bf16.
//                  B: (hi+lo)+ff(f32) -> LN -> sigmoid -> bf16 (in-place-safe)
// ---------------------------------------------------------------------------
__global__ __launch_bounds__(256) void add_ln_a(const float* __restrict__ X,
    const float* __restrict__ A, const float* __restrict__ g,
    const float* __restrict__ be, u16* __restrict__ Ohi, u16* __restrict__ Olo)
{
    const int row = blockIdx.x * 4 + (threadIdx.x >> 6);
    const int lane = threadIdx.x & 63;
    const float* xr = X + (size_t)row * PL;
    const float* ar = A + (size_t)row * PL;
    float v[8];
    float sum = 0.f;
    #pragma unroll
    for (int u = 0; u < 8; u++) { v[u] = xr[lane + u * 64] + ar[lane + u * 64]; sum += v[u]; }
    #pragma unroll
    for (int o = 32; o > 0; o >>= 1) sum += __shfl_xor(sum, o);
    const float mu = sum * (1.f / 512.f);
    float s2 = 0.f;
    #pragma unroll
    for (int u = 0; u < 8; u++) { float d = v[u] - mu; s2 = fmaf(d, d, s2); }
    #pragma unroll
    for (int o = 32; o > 0; o >>= 1) s2 += __shfl_xor(s2, o);
    const float rstd = rsqrtf(s2 * (1.f / 512.f) + 1e-5f);
    #pragma unroll
    for (int u = 0; u < 8; u++) {
        const int c = lane + u * 64;
        float y = (v[u] - mu) * rstd * g[c] + be[c];
        u16 hv = f2bf(y);
        Ohi[(size_t)row * PL + c] = hv;
        Olo[(size_t)row * PL + c] = f2bf(y - bf2f(hv));
    }
}

__global__ __launch_bounds__(256) void add_ln_b(const u16* __restrict__ Xhi,
    const u16* __restrict__ Xlo, const float* __restrict__ A,
    const float* __restrict__ g, const float* __restrict__ be, u16* __restrict__ TD)
{
    const int row = blockIdx.x * 4 + (threadIdx.x >> 6);
    const int lane = threadIdx.x & 63;
    const size_t ro = (size_t)row * PL;
    float v[8];
    float sum = 0.f;
    #pragma unroll
    for (int u = 0; u < 8; u++) {
        const int c = lane + u * 64;
        v[u] = bf2f(Xhi[ro + c]) + bf2f(Xlo[ro + c]) + A[ro + c];
        sum += v[u];
    }
    #pragma unroll
    for (int o = 32; o > 0; o >>= 1) sum += __shfl_xor(sum, o);
    const float mu = sum * (1.f / 512.f);
    float s2 = 0.f;
    #pragma unroll
    for (int u = 0; u < 8; u++) { float d = v[u] - mu; s2 = fmaf(d, d, s2); }
    #pragma unroll
    for (int o = 32; o > 0; o >>= 1) s2 += __shfl_xor(s2, o);
    const float rstd = rsqrtf(s2 * (1.f / 512.f) + 1e-5f);
    #pragma unroll
    for (int u = 0; u < 8; u++) {
        const int c = lane + u * 64;
        float y = (v[u] - mu) * rstd * g[c] + be[c];
        TD[ro + c] = f2bf(1.f / (1.f + expf(-y)));
    }
}

// ---------------------------------------------------------------------------
// sim: per batch, C[i][j] = dot(td1[i,:], td2[j,:]) / 512  (plain bf16 MFMA)
// ---------------------------------------------------------------------------
__global__ __launch_bounds__(256) void sim_mfma(const u16* __restrict__ TD1,
    const u16* __restrict__ TD2, float* __restrict__ Out)
{
    __shared__ u16 Ah[128 * 64], Bh[128 * 64];
    const int t = threadIdx.x, l = t & 63, w = t >> 6;
    const int lr = l & 15, lg = l >> 4;
    const int wm = w >> 1, wn = w & 1;
    const int bz = blockIdx.z;
    const u16* A = TD1 + (size_t)bz * NTOK * PL;
    const u16* B = TD2 + (size_t)bz * NTOK * PL;
    const int m0 = blockIdx.x * 128, n0 = blockIdx.y * 128;

    f32x4 acc[4][4];
    #pragma unroll
    for (int i = 0; i < 4; i++)
        #pragma unroll
        for (int j = 0; j < 4; j++) acc[i][j] = f32x4{0.f, 0.f, 0.f, 0.f};

    const int sr = t >> 3, sc = t & 7;
    for (int k0 = 0; k0 < 512; k0 += 64) {
        __syncthreads();
        #pragma unroll
        for (int q = 0; q < 4; q++) {
            const int r = sr + 32 * q;
            const int d = r * 64 + ((sc ^ (r & 7)) << 3);
            *(s16x8*)&Ah[d] = *(const s16x8*)&A[(size_t)(m0 + r) * 512 + k0 + sc * 8];
            *(s16x8*)&Bh[d] = *(const s16x8*)&B[(size_t)(n0 + r) * 512 + k0 + sc * 8];
        }
        __syncthreads();
        #pragma unroll
        for (int kk = 0; kk < 2; kk++) {
            const int ch = kk * 4 + lg;
            s16x8 af[4], bf[4];
            #pragma unroll
            for (int fm = 0; fm < 4; fm++) {
                const int r = wm * 64 + fm * 16 + lr;
                af[fm] = *(const s16x8*)&Ah[r * 64 + ((ch ^ (r & 7)) << 3)];
            }
            #pragma unroll
            for (int fn = 0; fn < 4; fn++) {
                const int r = wn * 64 + fn * 16 + lr;
                bf[fn] = *(const s16x8*)&Bh[r * 64 + ((ch ^ (r & 7)) << 3)];
            }
            #pragma unroll
            for (int fm = 0; fm < 4; fm++)
                #pragma unroll
                for (int fn = 0; fn < 4; fn++)
                    acc[fm][fn] = __builtin_amdgcn_mfma_f32_16x16x32_bf16(af[fm], bf[fn], acc[fm][fn], 0, 0, 0);
        }
    }
    #pragma unroll
    for (int fm = 0; fm < 4; fm++)
        #pragma unroll
        for (int fn = 0; fn < 4; fn++)
            #pragma unroll
            for (int rg = 0; rg < 4; rg++) {
                const int r = m0 + wm * 64 + fm * 16 + lg * 4 + rg;
                const int c = n0 + wn * 64 + fn * 16 + lr;
                Out[((size_t)(bz * NTOK + r)) * NTOK + c] = acc[fm][fn][rg] * (1.f / 512.f);
            }
}

// ---------------------------------------------------------------------------
extern "C" void kernel_launch(void* const* d_in, const int* in_sizes, int n_in,
                              void* d_out, int out_size, void* d_ws, size_t ws_size,
                              hipStream_t stream)
{
    const float* x = (const float*)d_in[0];
    const float* wqkv[2] = {(const float*)d_in[1],  (const float*)d_in[11]};
    const float* bqkv[2] = {(const float*)d_in[2],  (const float*)d_in[12]};
    const float* ga[2]   = {(const float*)d_in[3],  (const float*)d_in[13]};
    const float* bea[2]  = {(const float*)d_in[4],  (const float*)d_in[14]};
    const float* w1[2]   = {(const float*)d_in[5],  (const float*)d_in[15]};
    const float* b1[2]   = {(const float*)d_in[6],  (const float*)d_in[16]};
    const float* w2[2]   = {(const float*)d_in[7],  (const float*)d_in[17]};
    const float* b2[2]   = {(const float*)d_in[8],  (const float*)d_in[18]};
    const float* gb[2]   = {(const float*)d_in[9],  (const float*)d_in[19]};
    const float* beb[2]  = {(const float*)d_in[10], (const float*)d_in[20]};

    // workspace layout (40 MB total, matches previously-proven footprint)
    char* wsb = (char*)d_ws;
    u16*  xhi = (u16*)(wsb);                       // 4 MB
    u16*  xlo = (u16*)(wsb + (4ull << 20));        // 4 MB
    u16*  wqh = (u16*)(wsb + (8ull << 20));        // 1.5 MB
    u16*  wql = (u16*)(wsb + (10ull << 20));       // 1.5 MB
    u16*  w1h = (u16*)(wsb + (12ull << 20));       // 0.5 MB
    u16*  w1l = (u16*)(wsb + (13ull << 20));
    u16*  w2h = (u16*)(wsb + (14ull << 20));
    u16*  w2l = (u16*)(wsb + (15ull << 20));
    float* AOf = (float*)(wsb + (16ull << 20));    // 8 MB (attn out, then FF out)
    u16*  x1h = (u16*)(wsb + (24ull << 20));       // 4 MB (later aliased as TD2)
    u16*  x1l = (u16*)(wsb + (28ull << 20));       // 4 MB
    u16*  hlo = (u16*)(wsb + (32ull << 20));       // 4 MB
    u16*  td1 = (u16*)(wsb + (36ull << 20));       // 4 MB
    u16*  td2 = x1h;                               // alias (safe: elementwise in-place)

    char* ob = (char*)d_out;                       // 16 MB
    u16*  Qb  = (u16*)(ob);                        // 4 MB
    u16*  Kb  = (u16*)(ob + (4ull << 20));         // 4 MB
    u16*  Vt  = (u16*)(ob + (8ull << 20));         // 4 MB
    u16*  hhi = (u16*)(ob + (12ull << 20));        // 4 MB
    float* out = (float*)d_out;

    convert_x<<<2048, 256, 0, stream>>>(x, xhi, xlo);

    for (int L = 0; L < 2; L++) {
        convert_wt<<<dim3(16, 48), 256, 0, stream>>>(wqkv[L], wqh, wql, 1536);
        convert_wt<<<dim3(16, 16), 256, 0, stream>>>(w1[L], w1h, w1l, 512);
        convert_wt<<<dim3(16, 16), 256, 0, stream>>>(w2[L], w2h, w2l, 512);

        gemm_split<128, 0><<<dim3(32, 12), 256, 0, stream>>>(
            xhi, xlo, wqh, wql, bqkv[L], 1536, nullptr, Qb, Kb, Vt);
        if (L == 0) attn_mfma<1><<<dim3(32, 16), 256, 0, stream>>>(Qb, Kb, Vt, AOf);
        else        attn_mfma<0><<<dim3(32, 16), 256, 0, stream>>>(Qb, Kb, Vt, AOf);
        add_ln_a<<<1024, 256, 0, stream>>>(x, AOf, ga[L], bea[L], x1h, x1l);
        gemm_split<64, 1><<<dim3(64, 4), 256, 0, stream>>>(
            x1h, x1l, w1h, w1l, b1[L], 512, nullptr, hhi, hlo, nullptr);
        gemm_split<64, 2><<<dim3(64, 4), 256, 0, stream>>>(
            hhi, hlo, w2h, w2l, b2[L], 512, AOf, nullptr, nullptr, nullptr);
        add_ln_b<<<1024, 256, 0, stream>>>(x1h, x1l, AOf, gb[L], beb[L],
                                           (L == 0) ? td1 : td2);
    }
    sim_mfma<<<dim3(8, 8, 4), 256, 0, stream>>>(td1, td2, out);
}

// Round 4
// 196.972 us; speedup vs baseline: 11.5744x; 1.5128x over previous
//
#include <hip/hip_runtime.h>
#include <math.h>

// ---------------------------------------------------------------------------
// bf16-MFMA implementation, both transformer layers merged into z=2 dispatches.
//  - dense GEMMs (qkv, ff1, ff2): split-bf16 (hi/lo) 3-term MFMA => ~fp32 accuracy
//  - attention + sim: plain bf16 MFMA; attention K/V staged in LDS via
//    global_load_lds (pre-swizzled source, XOR-chunk read), double-buffered.
// ---------------------------------------------------------------------------

typedef float f32x4 __attribute__((ext_vector_type(4)));
typedef short s16x8 __attribute__((ext_vector_type(8)));
typedef unsigned short u16;
typedef unsigned int u32;

#define NTOK 1024
#define PL 512
#define QSCALE 0.04419417382415922f  // 1/sqrt(512)

__device__ inline u16 f2bf(float f) {
    unsigned u = __builtin_bit_cast(unsigned, f);
    unsigned r = u + 0x7fffu + ((u >> 16) & 1u);   // RNE
    return (u16)(r >> 16);
}
__device__ inline float bf2f(u16 h) {
    unsigned u = ((unsigned)h) << 16;
    return __builtin_bit_cast(float, u);
}

__device__ inline void gll16(const void* g, void* l) {
    __builtin_amdgcn_global_load_lds(
        (const __attribute__((address_space(1))) u32*)g,
        (__attribute__((address_space(3))) u32*)l, 16, 0, 0);
}

// ---------------------------------------------------------------------------
// x -> hi/lo bf16 split (elementwise)
// ---------------------------------------------------------------------------
__global__ __launch_bounds__(256) void convert_x(const float* __restrict__ X,
    u16* __restrict__ hi, u16* __restrict__ lo)
{
    const int i = (blockIdx.x * 256 + threadIdx.x) * 4;
    float4 v = *(const float4*)&X[i];
    float vv[4] = {v.x, v.y, v.z, v.w};
    #pragma unroll
    for (int j = 0; j < 4; j++) {
        u16 h = f2bf(vv[j]);
        hi[i + j] = h;
        lo[i + j] = f2bf(vv[j] - bf2f(h));
    }
}

// ---------------------------------------------------------------------------
// W [512][N] f32 -> Wt [N][512] bf16 hi/lo (tiled transpose), z = layer
// ---------------------------------------------------------------------------
__global__ __launch_bounds__(256) void convert_wt(const float* __restrict__ W0,
    const float* __restrict__ W1, u16* __restrict__ WhiB, u16* __restrict__ WloB,
    const size_t dLS, const int N)
{
    const float* W = blockIdx.z ? W1 : W0;
    u16* Whi = WhiB + (size_t)blockIdx.z * dLS;
    u16* Wlo = WloB + (size_t)blockIdx.z * dLS;
    __shared__ float T[32][36];
    const int k0 = blockIdx.x * 32, n0 = blockIdx.y * 32;
    const int tr = threadIdx.x >> 3, tc = (threadIdx.x & 7) * 4;
    *(float4*)&T[tr][tc] = *(const float4*)&W[(size_t)(k0 + tr) * N + n0 + tc];
    __syncthreads();
    u16 hv[4], lv[4];
    #pragma unroll
    for (int j = 0; j < 4; j++) {
        float v = T[tc + j][tr];
        hv[j] = f2bf(v);
        lv[j] = f2bf(v - bf2f(hv[j]));
    }
    const size_t o = (size_t)(n0 + tr) * 512 + k0 + tc;
    #pragma unroll
    for (int j = 0; j < 4; j++) { Whi[o + j] = hv[j]; Wlo[o + j] = lv[j]; }
}

// ---------------------------------------------------------------------------
// Split-bf16 MFMA GEMM, z = layer. A[4096][512] (hi/lo) x Bt[N][512] (hi/lo).
// EPI: 0 = qkv scatter (Q scaled, K, Vt), 1 = gelu -> hi/lo, 2 = plain hi/lo.
// ---------------------------------------------------------------------------
template<int BM, int EPI>
__global__ __launch_bounds__(256) void gemm_split(
    const u16* __restrict__ AhiB, const u16* __restrict__ AloB, const size_t aLS,
    const u16* __restrict__ BhiB, const u16* __restrict__ BloB, const size_t bLS,
    const float* __restrict__ bias0, const float* __restrict__ bias1, const int Ncols,
    u16* __restrict__ qq, u16* __restrict__ kkp, u16* __restrict__ vvp,
    u16* __restrict__ oh0, u16* __restrict__ oh1,
    u16* __restrict__ ol0, u16* __restrict__ ol1)
{
    constexpr int FM = BM / 32;
    __shared__ u16 Ah[BM * 64], Al[BM * 64], Bh[128 * 64], Bl[128 * 64];
    const int z = blockIdx.z;
    const u16* Ahi = AhiB + (size_t)z * aLS;
    const u16* Alo = AloB + (size_t)z * aLS;
    const u16* Bhi = BhiB + (size_t)z * bLS;
    const u16* Blo = BloB + (size_t)z * bLS;
    const float* bias = z ? bias1 : bias0;
    u16* oh = z ? oh1 : oh0;
    u16* ol = z ? ol1 : ol0;

    const int t = threadIdx.x, l = t & 63, w = t >> 6;
    const int lr = l & 15, lg = l >> 4;
    const int wm = w >> 1, wn = w & 1;
    const int m0 = blockIdx.x * BM, n0 = blockIdx.y * 128;

    f32x4 acc[FM][4];
    #pragma unroll
    for (int i = 0; i < FM; i++)
        #pragma unroll
        for (int j = 0; j < 4; j++) acc[i][j] = f32x4{0.f, 0.f, 0.f, 0.f};

    const int sr = t >> 3, sc = t & 7;
    for (int k0 = 0; k0 < 512; k0 += 64) {
        __syncthreads();
        #pragma unroll
        for (int q = 0; q < BM / 32; q++) {
            const int r = sr + 32 * q;
            const int d = r * 64 + ((sc ^ (r & 7)) << 3);
            const size_t g = (size_t)(m0 + r) * 512 + k0 + sc * 8;
            *(s16x8*)&Ah[d] = *(const s16x8*)&Ahi[g];
            *(s16x8*)&Al[d] = *(const s16x8*)&Alo[g];
        }
        #pragma unroll
        for (int q = 0; q < 4; q++) {
            const int r = sr + 32 * q;
            const int d = r * 64 + ((sc ^ (r & 7)) << 3);
            const size_t g = (size_t)(n0 + r) * 512 + k0 + sc * 8;
            *(s16x8*)&Bh[d] = *(const s16x8*)&Bhi[g];
            *(s16x8*)&Bl[d] = *(const s16x8*)&Blo[g];
        }
        __syncthreads();
        #pragma unroll
        for (int kk = 0; kk < 2; kk++) {
            s16x8 ah[FM], al[FM], bh[4], bl[4];
            const int ch = kk * 4 + lg;
            #pragma unroll
            for (int fm = 0; fm < FM; fm++) {
                const int r = wm * (BM / 2) + fm * 16 + lr;
                const int d = r * 64 + ((ch ^ (r & 7)) << 3);
                ah[fm] = *(const s16x8*)&Ah[d];
                al[fm] = *(const s16x8*)&Al[d];
            }
            #pragma unroll
            for (int fn = 0; fn < 4; fn++) {
                const int r = wn * 64 + fn * 16 + lr;
                const int d = r * 64 + ((ch ^ (r & 7)) << 3);
                bh[fn] = *(const s16x8*)&Bh[d];
                bl[fn] = *(const s16x8*)&Bl[d];
            }
            #pragma unroll
            for (int fm = 0; fm < FM; fm++)
                #pragma unroll
                for (int fn = 0; fn < 4; fn++) {
                    acc[fm][fn] = __builtin_amdgcn_mfma_f32_16x16x32_bf16(ah[fm], bh[fn], acc[fm][fn], 0, 0, 0);
                    acc[fm][fn] = __builtin_amdgcn_mfma_f32_16x16x32_bf16(ah[fm], bl[fn], acc[fm][fn], 0, 0, 0);
                    acc[fm][fn] = __builtin_amdgcn_mfma_f32_16x16x32_bf16(al[fm], bh[fn], acc[fm][fn], 0, 0, 0);
                }
        }
    }
    // epilogue
    #pragma unroll
    for (int fm = 0; fm < FM; fm++)
        #pragma unroll
        for (int fn = 0; fn < 4; fn++)
            #pragma unroll
            for (int rg = 0; rg < 4; rg++) {
                const int r = m0 + wm * (BM / 2) + fm * 16 + lg * 4 + rg;
                const int c = n0 + wn * 64 + fn * 16 + lr;
                float v = acc[fm][fn][rg] + bias[c];
                if constexpr (EPI == 0) {
                    const int part = c >> 9, c2 = c & 511;
                    const int h = c2 & 7, dd = c2 >> 3;
                    const int b = r >> 10, n = r & 1023;
                    const size_t bh_ = (size_t)(b * 8 + h);
                    const size_t zo = (size_t)z * 2097152;
                    if (part == 0)      qq [zo + (bh_ * 1024 + n) * 64 + dd] = f2bf(v * QSCALE);
                    else if (part == 1) kkp[zo + (bh_ * 1024 + n) * 64 + dd] = f2bf(v);
                    else                vvp[zo + (bh_ * 64 + dd) * 1024 + n] = f2bf(v);
                } else {
                    float gl = v;
                    if constexpr (EPI == 1)
                        gl = 0.5f * v * (1.f + erff(v * 0.70710678118654752f));
                    u16 hv = f2bf(gl);
                    oh[(size_t)r * Ncols + c] = hv;
                    ol[(size_t)r * Ncols + c] = f2bf(gl - bf2f(hv));
                }
            }
}

// ---------------------------------------------------------------------------
// Flash attention, bf16 MFMA, z = layer (z==0 causal, z==1 anti-causal).
// K/Vt tiles staged in LDS cooperatively via global_load_lds, double-buffered,
// pre-swizzled source / XOR-chunk-swizzled reads. 4 waves x 16 q-rows.
// ---------------------------------------------------------------------------
__global__ __launch_bounds__(256) void attn_mfma(const u16* __restrict__ Qg,
    const u16* __restrict__ Kg, const u16* __restrict__ Vtg,
    float* __restrict__ AO0, float* __restrict__ AO1)
{
    __shared__ u16 Ks[2][64 * 64];
    __shared__ u16 Vs[2][64 * 64];
    __shared__ u16 Ps[4][16 * 72];
    const int t = threadIdx.x, l = t & 63, w = t >> 6;
    const int lr = l & 15, lg = l >> 4;
    const int z = blockIdx.z;
    const int causal = (z == 0);
    const int bh = blockIdx.x;
    const int b = bh >> 3, h = bh & 7;
    const int qt = causal ? (15 - (int)blockIdx.y) : (int)blockIdx.y;  // long jobs first
    const u16* Qb = Qg + (size_t)(z * 32 + bh) * (NTOK * 64);
    const u16* Kb = Kg + (size_t)(z * 32 + bh) * (NTOK * 64);
    const u16* Vb = Vtg + (size_t)(z * 32 + bh) * (64 * NTOK);
    float* AO = z ? AO1 : AO0;
    const int q0 = qt * 64 + w * 16;

    // Q fragments (reused across all k-tiles)
    s16x8 aq[2];
    aq[0] = *(const s16x8*)&Qb[(size_t)(q0 + lr) * 64 + lg * 8];
    aq[1] = *(const s16x8*)&Qb[(size_t)(q0 + lr) * 64 + 32 + lg * 8];

    f32x4 o[4];
    float m_[4], l_[4];
    #pragma unroll
    for (int f = 0; f < 4; f++) o[f] = f32x4{0.f, 0.f, 0.f, 0.f};
    #pragma unroll
    for (int r = 0; r < 4; r++) { m_[r] = -INFINITY; l_[r] = 0.f; }

    const int kt0 = causal ? 0 : qt, kt1 = causal ? qt : 15;

    // stage tile kt into buffer bufi (wave-cooperative; per wave 2+2 issues)
    auto stage = [&](int bufi, int kt) {
        #pragma unroll
        for (int i = 0; i < 2; i++) {
            const int j = w * 2 + i;                 // 1KB chunk index (wave-uniform)
            const int r = j * 8 + (l >> 3);          // key row in tile
            const int ck = (l & 7) ^ (r & 7);        // pre-swizzled source chunk
            gll16(Kb + (size_t)(kt * 64 + r) * 64 + ck * 8, &Ks[bufi][j * 512]);
        }
        #pragma unroll
        for (int i = 0; i < 2; i++) {
            const int j = w * 2 + i;
            const int dim = j * 8 + (l >> 3);        // dim row in Vt tile
            const int ck = (l & 7) ^ (dim & 7);
            gll16(Vb + (size_t)dim * NTOK + kt * 64 + ck * 8, &Vs[bufi][j * 512]);
        }
    };

    stage(0, kt0);
    __syncthreads();
    int buf = 0;
    for (int kt = kt0; kt <= kt1; kt++) {
        if (kt < kt1) stage(buf ^ 1, kt + 1);
        // ---- S = Q K^T ----
        f32x4 s[4];
        #pragma unroll
        for (int f = 0; f < 4; f++) s[f] = f32x4{0.f, 0.f, 0.f, 0.f};
        #pragma unroll
        for (int kk = 0; kk < 2; kk++)
            #pragma unroll
            for (int f = 0; f < 4; f++) {
                const int row = f * 16 + lr;
                const int ch = kk * 4 + lg;
                s16x8 bk = *(const s16x8*)&Ks[buf][row * 64 + ((ch ^ (row & 7)) << 3)];
                s[f] = __builtin_amdgcn_mfma_f32_16x16x32_bf16(aq[kk], bk, s[f], 0, 0, 0);
            }
        // ---- mask on diagonal tile ----
        if (kt == qt) {
            #pragma unroll
            for (int f = 0; f < 4; f++) {
                const int key = kt * 64 + f * 16 + lr;
                #pragma unroll
                for (int r = 0; r < 4; r++) {
                    const int q = q0 + lg * 4 + r;
                    if (causal ? (key > q) : (key < q)) s[f][r] = -INFINITY;
                }
            }
        }
        // ---- online softmax (per reg r = q-row) ----
        float scale[4];
        #pragma unroll
        for (int r = 0; r < 4; r++) {
            float rm = fmaxf(fmaxf(s[0][r], s[1][r]), fmaxf(s[2][r], s[3][r]));
            #pragma unroll
            for (int off = 1; off < 16; off <<= 1) rm = fmaxf(rm, __shfl_xor(rm, off));
            const float mn = fmaxf(m_[r], rm);
            scale[r] = __expf(m_[r] - mn);
            float ps = 0.f;
            #pragma unroll
            for (int f = 0; f < 4; f++) { float p = __expf(s[f][r] - mn); s[f][r] = p; ps += p; }
            #pragma unroll
            for (int off = 1; off < 16; off <<= 1) ps += __shfl_xor(ps, off);
            l_[r] = l_[r] * scale[r] + ps;
            m_[r] = mn;
        }
        // ---- P -> wave-private LDS (bf16), rescale O ----
        #pragma unroll
        for (int f = 0; f < 4; f++)
            #pragma unroll
            for (int r = 0; r < 4; r++)
                Ps[w][(lg * 4 + r) * 72 + f * 16 + lr] = f2bf(s[f][r]);
        #pragma unroll
        for (int f = 0; f < 4; f++)
            #pragma unroll
            for (int r = 0; r < 4; r++) o[f][r] *= scale[r];
        // ---- O += P V ----
        #pragma unroll
        for (int kk = 0; kk < 2; kk++) {
            s16x8 ap = *(const s16x8*)&Ps[w][lr * 72 + kk * 32 + lg * 8];
            #pragma unroll
            for (int f = 0; f < 4; f++) {
                const int row = f * 16 + lr;
                const int ch = kk * 4 + lg;
                s16x8 bv = *(const s16x8*)&Vs[buf][row * 64 + ((ch ^ (row & 7)) << 3)];
                o[f] = __builtin_amdgcn_mfma_f32_16x16x32_bf16(ap, bv, o[f], 0, 0, 0);
            }
        }
        __syncthreads();   // drains stage loads; all waves done with buf
        buf ^= 1;
    }
    // ---- epilogue: head-SLOW merge, f32 ----
    #pragma unroll
    for (int f = 0; f < 4; f++)
        #pragma unroll
        for (int r = 0; r < 4; r++)
            AO[(size_t)(b * NTOK + q0 + lg * 4 + r) * PL + h * 64 + f * 16 + lr] = o[f][r] / l_[r];
}

// ---------------------------------------------------------------------------
// add+LN A: x(f32)+attn(f32) -> LN -> hi/lo bf16. z = layer.
// ---------------------------------------------------------------------------
__global__ __launch_bounds__(256) void add_ln_a(const float* __restrict__ X,
    const float* __restrict__ A0, const float* __restrict__ A1,
    const float* __restrict__ g0, const float* __restrict__ g1,
    const float* __restrict__ be0, const float* __restrict__ be1,
    u16* __restrict__ OhiB, u16* __restrict__ OloB, const size_t oLS)
{
    const int z = blockIdx.z;
    const float* A = z ? A1 : A0;
    const float* g = z ? g1 : g0;
    const float* be = z ? be1 : be0;
    u16* Ohi = OhiB + (size_t)z * oLS;
    u16* Olo = OloB + (size_t)z * oLS;
    const int row = blockIdx.x * 4 + (threadIdx.x >> 6);
    const int lane = threadIdx.x & 63;
    const float* xr = X + (size_t)row * PL;
    const float* ar = A + (size_t)row * PL;
    float v[8];
    float sum = 0.f;
    #pragma unroll
    for (int u = 0; u < 8; u++) { v[u] = xr[lane + u * 64] + ar[lane + u * 64]; sum += v[u]; }
    #pragma unroll
    for (int o = 32; o > 0; o >>= 1) sum += __shfl_xor(sum, o);
    const float mu = sum * (1.f / 512.f);
    float s2 = 0.f;
    #pragma unroll
    for (int u = 0; u < 8; u++) { float d = v[u] - mu; s2 = fmaf(d, d, s2); }
    #pragma unroll
    for (int o = 32; o > 0; o >>= 1) s2 += __shfl_xor(s2, o);
    const float rstd = rsqrtf(s2 * (1.f / 512.f) + 1e-5f);
    #pragma unroll
    for (int u = 0; u < 8; u++) {
        const int c = lane + u * 64;
        float y = (v[u] - mu) * rstd * g[c] + be[c];
        u16 hv = f2bf(y);
        Ohi[(size_t)row * PL + c] = hv;
        Olo[(size_t)row * PL + c] = f2bf(y - bf2f(hv));
    }
}

// ---------------------------------------------------------------------------
// add+LN B: (x1 hi+lo) + (ff hi+lo) -> LN -> sigmoid -> bf16 td. z = layer.
// ---------------------------------------------------------------------------
__global__ __launch_bounds__(256) void add_ln_b(
    const u16* __restrict__ XhiB, const u16* __restrict__ XloB, const size_t xLS,
    const u16* __restrict__ F0h, const u16* __restrict__ F1h,
    const u16* __restrict__ F0l, const u16* __restrict__ F1l,
    const float* __restrict__ g0, const float* __restrict__ g1,
    const float* __restrict__ be0, const float* __restrict__ be1,
    u16* __restrict__ TD0, u16* __restrict__ TD1)
{
    const int z = blockIdx.z;
    const u16* Xhi = XhiB + (size_t)z * xLS;
    const u16* Xlo = XloB + (size_t)z * xLS;
    const u16* Fh = z ? F1h : F0h;
    const u16* Fl = z ? F1l : F0l;
    const float* g = z ? g1 : g0;
    const float* be = z ? be1 : be0;
    u16* TD = z ? TD1 : TD0;
    const int row = blockIdx.x * 4 + (threadIdx.x >> 6);
    const int lane = threadIdx.x & 63;
    const size_t ro = (size_t)row * PL;
    float v[8];
    float sum = 0.f;
    #pragma unroll
    for (int u = 0; u < 8; u++) {
        const int c = lane + u * 64;
        v[u] = bf2f(Xhi[ro + c]) + bf2f(Xlo[ro + c]) + bf2f(Fh[ro + c]) + bf2f(Fl[ro + c]);
        sum += v[u];
    }
    #pragma unroll
    for (int o = 32; o > 0; o >>= 1) sum += __shfl_xor(sum, o);
    const float mu = sum * (1.f / 512.f);
    float s2 = 0.f;
    #pragma unroll
    for (int u = 0; u < 8; u++) { float d = v[u] - mu; s2 = fmaf(d, d, s2); }
    #pragma unroll
    for (int o = 32; o > 0; o >>= 1) s2 += __shfl_xor(s2, o);
    const float rstd = rsqrtf(s2 * (1.f / 512.f) + 1e-5f);
    #pragma unroll
    for (int u = 0; u < 8; u++) {
        const int c = lane + u * 64;
        float y = (v[u] - mu) * rstd * g[c] + be[c];
        TD[ro + c] = f2bf(1.f / (1.f + expf(-y)));
    }
}

// ---------------------------------------------------------------------------
// sim: per batch, C[i][j] = dot(td1[i,:], td2[j,:]) / 512  (plain bf16 MFMA)
// ---------------------------------------------------------------------------
__global__ __launch_bounds__(256) void sim_mfma(const u16* __restrict__ TD1,
    const u16* __restrict__ TD2, float* __restrict__ Out)
{
    __shared__ u16 Ah[128 * 64], Bh[128 * 64];
    const int t = threadIdx.x, l = t & 63, w = t >> 6;
    const int lr = l & 15, lg = l >> 4;
    const int wm = w >> 1, wn = w & 1;
    const int bz = blockIdx.z;
    const u16* A = TD1 + (size_t)bz * NTOK * PL;
    const u16* B = TD2 + (size_t)bz * NTOK * PL;
    const int m0 = blockIdx.x * 128, n0 = blockIdx.y * 128;

    f32x4 acc[4][4];
    #pragma unroll
    for (int i = 0; i < 4; i++)
        #pragma unroll
        for (int j = 0; j < 4; j++) acc[i][j] = f32x4{0.f, 0.f, 0.f, 0.f};

    const int sr = t >> 3, sc = t & 7;
    for (int k0 = 0; k0 < 512; k0 += 64) {
        __syncthreads();
        #pragma unroll
        for (int q = 0; q < 4; q++) {
            const int r = sr + 32 * q;
            const int d = r * 64 + ((sc ^ (r & 7)) << 3);
            *(s16x8*)&Ah[d] = *(const s16x8*)&A[(size_t)(m0 + r) * 512 + k0 + sc * 8];
            *(s16x8*)&Bh[d] = *(const s16x8*)&B[(size_t)(n0 + r) * 512 + k0 + sc * 8];
        }
        __syncthreads();
        #pragma unroll
        for (int kk = 0; kk < 2; kk++) {
            const int ch = kk * 4 + lg;
            s16x8 af[4], bf[4];
            #pragma unroll
            for (int fm = 0; fm < 4; fm++) {
                const int r = wm * 64 + fm * 16 + lr;
                af[fm] = *(const s16x8*)&Ah[r * 64 + ((ch ^ (r & 7)) << 3)];
            }
            #pragma unroll
            for (int fn = 0; fn < 4; fn++) {
                const int r = wn * 64 + fn * 16 + lr;
                bf[fn] = *(const s16x8*)&Bh[r * 64 + ((ch ^ (r & 7)) << 3)];
            }
            #pragma unroll
            for (int fm = 0; fm < 4; fm++)
                #pragma unroll
                for (int fn = 0; fn < 4; fn++)
                    acc[fm][fn] = __builtin_amdgcn_mfma_f32_16x16x32_bf16(af[fm], bf[fn], acc[fm][fn], 0, 0, 0);
        }
    }
    #pragma unroll
    for (int fm = 0; fm < 4; fm++)
        #pragma unroll
        for (int fn = 0; fn < 4; fn++)
            #pragma unroll
            for (int rg = 0; rg < 4; rg++) {
                const int r = m0 + wm * 64 + fm * 16 + lg * 4 + rg;
                const int c = n0 + wn * 64 + fn * 16 + lr;
                Out[((size_t)(bz * NTOK + r)) * NTOK + c] = acc[fm][fn][rg] * (1.f / 512.f);
            }
}

// ---------------------------------------------------------------------------
extern "C" void kernel_launch(void* const* d_in, const int* in_sizes, int n_in,
                              void* d_out, int out_size, void* d_ws, size_t ws_size,
                              hipStream_t stream)
{
    const float* x = (const float*)d_in[0];
    const float* wqkv[2] = {(const float*)d_in[1],  (const float*)d_in[11]};
    const float* bqkv[2] = {(const float*)d_in[2],  (const float*)d_in[12]};
    const float* ga[2]   = {(const float*)d_in[3],  (const float*)d_in[13]};
    const float* bea[2]  = {(const float*)d_in[4],  (const float*)d_in[14]};
    const float* w1[2]   = {(const float*)d_in[5],  (const float*)d_in[15]};
    const float* b1[2]   = {(const float*)d_in[6],  (const float*)d_in[16]};
    const float* w2[2]   = {(const float*)d_in[7],  (const float*)d_in[17]};
    const float* b2[2]   = {(const float*)d_in[8],  (const float*)d_in[18]};
    const float* gb[2]   = {(const float*)d_in[9],  (const float*)d_in[19]};
    const float* beb[2]  = {(const float*)d_in[10], (const float*)d_in[20]};

    // -------- workspace map (KB offsets; lifetimes verified stage-by-stage) --
    char* wsb = (char*)d_ws;
    char* ob  = (char*)d_out;
    #define WSK(kb) ((char*)wsb + ((size_t)(kb) << 10))
    #define OBK(kb) ((char*)ob  + ((size_t)(kb) << 10))
    // ws: [0,4M) wff (S1-S6) -> td1 (S7-)
    u16* w1h = (u16*)WSK(0);      // + z*1048576 elems
    u16* w1l = (u16*)WSK(512);
    u16* w2h = (u16*)WSK(1024);
    u16* w2l = (u16*)WSK(1536);
    u16* td1 = (u16*)WSK(0);
    // ws: [4M,12M) xsplit (S0-S2) -> AO0 f32 (S3-S4) -> ffo0 hi/lo (S6-S7)
    u16*   xhi  = (u16*)WSK(4096);
    u16*   xlo  = (u16*)WSK(8192);
    float* AO0  = (float*)WSK(4096);
    u16*   ffo0h = (u16*)WSK(4096);
    u16*   ffo0l = (u16*)WSK(8192);
    // ws: [12M,18M) wq (S1-S2); [12M,16M) ffo1hi (S6-S7)
    u16* wqh = (u16*)WSK(12288);  // + z*786432 elems
    u16* wql = (u16*)WSK(13824);
    u16* ffo1h = (u16*)WSK(12288);
    // ws: [16M,32M) x1 hi/lo (S4-S7)
    u16* x1h = (u16*)WSK(16384);  // + z*4194304 elems
    u16* x1l = (u16*)WSK(20480);
    // ws: [18M,34M) Q,K (S2-S3)
    u16* Qb = (u16*)WSK(18432);   // + z*2097152 elems
    u16* Kb = (u16*)WSK(26624);
    // ws: [32M,36M) ffo1lo (S6-S7); [36M,40M) td2 (S7-)
    u16* ffo1l = (u16*)WSK(32768);
    u16* td2   = (u16*)WSK(36864);
    // d_out: Vt (S2-S3); AO1 (S3-S4); h hi/lo (S5-S6); final out (S8)
    u16*   Vt  = (u16*)OBK(0);    // + z*2097152 elems
    float* AO1 = (float*)OBK(8192);
    u16*   h0h = (u16*)OBK(0);
    u16*   h0l = (u16*)OBK(4096);
    u16*   h1h = (u16*)OBK(8192);
    u16*   h1l = (u16*)OBK(12288);
    float* out = (float*)d_out;

    // S0: x split
    convert_x<<<2048, 256, 0, stream>>>(x, xhi, xlo);
    // S1: weight transposes+splits (z = layer)
    convert_wt<<<dim3(16, 48, 2), 256, 0, stream>>>(wqkv[0], wqkv[1], wqh, wql, 786432, 1536);
    convert_wt<<<dim3(16, 16, 2), 256, 0, stream>>>(w1[0], w1[1], w1h, w1l, 1048576, 512);
    convert_wt<<<dim3(16, 16, 2), 256, 0, stream>>>(w2[0], w2[1], w2h, w2l, 1048576, 512);
    // S2: qkv gemm (both layers)
    gemm_split<128, 0><<<dim3(32, 12, 2), 256, 0, stream>>>(
        xhi, xlo, 0, wqh, wql, 786432, bqkv[0], bqkv[1], 1536,
        Qb, Kb, Vt, nullptr, nullptr, nullptr, nullptr);
    // S3: attention (both layers; z=0 causal, z=1 anti-causal)
    attn_mfma<<<dim3(32, 16, 2), 256, 0, stream>>>(Qb, Kb, Vt, AO0, AO1);
    // S4: add + LN -> x1 hi/lo
    add_ln_a<<<dim3(1024, 1, 2), 256, 0, stream>>>(x, AO0, AO1,
        ga[0], ga[1], bea[0], bea[1], x1h, x1l, 4194304);
    // S5: ff1 (gelu) -> h hi/lo (in d_out)
    gemm_split<64, 1><<<dim3(64, 4, 2), 256, 0, stream>>>(
        x1h, x1l, 4194304, w1h, w1l, 1048576, b1[0], b1[1], 512,
        nullptr, nullptr, nullptr, h0h, h1h, h0l, h1l);
    // S6: ff2 -> ffo hi/lo (in ws)
    gemm_split<64, 2><<<dim3(64, 4, 2), 256, 0, stream>>>(
        h0h, h0l, 4194304, w2h, w2l, 1048576, b2[0], b2[1], 512,
        nullptr, nullptr, nullptr, ffo0h, ffo1h, ffo0l, ffo1l);
    // S7: add + LN + sigmoid -> td
    add_ln_b<<<dim3(1024, 1, 2), 256, 0, stream>>>(
        x1h, x1l, 4194304, ffo0h, ffo1h, ffo0l, ffo1l,
        gb[0], gb[1], beb[0], beb[1], td1, td2);
    // S8: sim
    sim_mfma<<<dim3(8, 8, 4), 256, 0, stream>>>(td1, td2, out);
}

// Round 5
// 193.231 us; speedup vs baseline: 11.7985x; 1.0194x over previous
//
#include <hip/hip_runtime.h>
#include <math.h>

// ---------------------------------------------------------------------------
// bf16-MFMA implementation, both layers merged (z=2), global_load_lds staging.
//  - qkv GEMM: 3-term split-bf16 (hi/lo on A and B) => ~fp32 accuracy
//  - ff1/ff2:  2-term (A split, B single bf16) — error passes through LN+sigmoid
//  - attention + sim: plain bf16 MFMA
//  - BK=32 GEMM tiles, swizzle ch ^= (row>>1)&3 (2-way conflict = free)
// ---------------------------------------------------------------------------

typedef float f32x4 __attribute__((ext_vector_type(4)));
typedef short s16x8 __attribute__((ext_vector_type(8)));
typedef unsigned short u16;
typedef unsigned int u32;

#define NTOK 1024
#define PL 512
#define QSCALE 0.04419417382415922f  // 1/sqrt(512)

__device__ inline u16 f2bf(float f) {
    unsigned u = __builtin_bit_cast(unsigned, f);
    unsigned r = u + 0x7fffu + ((u >> 16) & 1u);   // RNE
    return (u16)(r >> 16);
}
__device__ inline float bf2f(u16 h) {
    unsigned u = ((unsigned)h) << 16;
    return __builtin_bit_cast(float, u);
}

__device__ inline void gll16(const void* g, void* l) {
    __builtin_amdgcn_global_load_lds(
        (const __attribute__((address_space(1))) u32*)g,
        (__attribute__((address_space(3))) u32*)l, 16, 0, 0);
}

// ---------------------------------------------------------------------------
// x -> hi/lo bf16 split (elementwise)
// ---------------------------------------------------------------------------
__global__ __launch_bounds__(256) void convert_x(const float* __restrict__ X,
    u16* __restrict__ hi, u16* __restrict__ lo)
{
    const int i = (blockIdx.x * 256 + threadIdx.x) * 4;
    float4 v = *(const float4*)&X[i];
    float vv[4] = {v.x, v.y, v.z, v.w};
    #pragma unroll
    for (int j = 0; j < 4; j++) {
        u16 h = f2bf(vv[j]);
        hi[i + j] = h;
        lo[i + j] = f2bf(vv[j] - bf2f(h));
    }
}

// ---------------------------------------------------------------------------
// W [512][N] f32 -> Wt [N][512] bf16 hi(/lo) (tiled transpose), z = layer
// ---------------------------------------------------------------------------
__global__ __launch_bounds__(256) void convert_wt(const float* __restrict__ W0,
    const float* __restrict__ W1, u16* __restrict__ WhiB, u16* __restrict__ WloB,
    const size_t dLS, const int N, const int writeLo)
{
    const float* W = blockIdx.z ? W1 : W0;
    u16* Whi = WhiB + (size_t)blockIdx.z * dLS;
    u16* Wlo = WloB ? (WloB + (size_t)blockIdx.z * dLS) : nullptr;
    __shared__ float T[32][36];
    const int k0 = blockIdx.x * 32, n0 = blockIdx.y * 32;
    const int tr = threadIdx.x >> 3, tc = (threadIdx.x & 7) * 4;
    *(float4*)&T[tr][tc] = *(const float4*)&W[(size_t)(k0 + tr) * N + n0 + tc];
    __syncthreads();
    u16 hv[4], lv[4];
    #pragma unroll
    for (int j = 0; j < 4; j++) {
        float v = T[tc + j][tr];
        hv[j] = f2bf(v);
        lv[j] = f2bf(v - bf2f(hv[j]));
    }
    const size_t o = (size_t)(n0 + tr) * 512 + k0 + tc;
    #pragma unroll
    for (int j = 0; j < 4; j++) Whi[o + j] = hv[j];
    if (writeLo)
        #pragma unroll
        for (int j = 0; j < 4; j++) Wlo[o + j] = lv[j];
}

// ---------------------------------------------------------------------------
// Split-bf16 MFMA GEMM, z = layer. A[4096][512] (hi/lo) x Bt[N][512].
// TERMS: 3 = ah*bh+ah*bl+al*bh, 2 = ah*bh+al*bh (B single bf16).
// EPI: 0 = qkv scatter (Q scaled, K, Vt), 1 = gelu -> hi/lo, 2 = plain hi/lo.
// BK=32; staging via global_load_lds (linear dest, pre-swizzled source).
// ---------------------------------------------------------------------------
template<int BM, int TERMS, int EPI>
__global__ __launch_bounds__(256) void gemm_split(
    const u16* __restrict__ AhiB, const u16* __restrict__ AloB, const size_t aLS,
    const u16* __restrict__ BhiB, const u16* __restrict__ BloB, const size_t bLS,
    const float* __restrict__ bias0, const float* __restrict__ bias1, const int Ncols,
    u16* __restrict__ qq, u16* __restrict__ kkp, u16* __restrict__ vvp,
    u16* __restrict__ oh0, u16* __restrict__ oh1,
    u16* __restrict__ ol0, u16* __restrict__ ol1)
{
    constexpr int FM = BM / 32;
    __shared__ u16 Ah[BM * 32], Al[BM * 32], Bh[128 * 32];
    __shared__ u16 Bl[(TERMS == 3) ? 128 * 32 : 64];
    const int z = blockIdx.z;
    const u16* Ahi = AhiB + (size_t)z * aLS;
    const u16* Alo = AloB + (size_t)z * aLS;
    const u16* Bhi = BhiB + (size_t)z * bLS;
    const u16* Blo = BloB ? (BloB + (size_t)z * bLS) : nullptr;
    const float* bias = z ? bias1 : bias0;
    u16* oh = z ? oh1 : oh0;
    u16* ol = z ? ol1 : ol0;

    const int t = threadIdx.x, l = t & 63, w = t >> 6;
    const int lr = l & 15, lg = l >> 4;
    const int wm = w >> 1, wn = w & 1;
    const int m0 = blockIdx.x * BM, n0 = blockIdx.y * 128;
    const int srow = l >> 2, sch = l & 3;    // staging lane coords (16 rows/KB)

    f32x4 acc[FM][4];
    #pragma unroll
    for (int i = 0; i < FM; i++)
        #pragma unroll
        for (int j = 0; j < 4; j++) acc[i][j] = f32x4{0.f, 0.f, 0.f, 0.f};

    for (int k0 = 0; k0 < 512; k0 += 32) {
        __syncthreads();
        #pragma unroll
        for (int i = 0; i < BM / 64; i++) {
            const int j = w * (BM / 64) + i;
            const int r = j * 16 + srow;
            const int ck = sch ^ ((r >> 1) & 3);
            const size_t g = (size_t)(m0 + r) * 512 + k0 + ck * 8;
            gll16(&Ahi[g], &Ah[j * 512]);
            gll16(&Alo[g], &Al[j * 512]);
        }
        #pragma unroll
        for (int i = 0; i < 2; i++) {
            const int j = w * 2 + i;
            const int r = j * 16 + srow;
            const int ck = sch ^ ((r >> 1) & 3);
            const size_t g = (size_t)(n0 + r) * 512 + k0 + ck * 8;
            gll16(&Bhi[g], &Bh[j * 512]);
            if constexpr (TERMS == 3) gll16(&Blo[g], &Bl[j * 512]);
        }
        __syncthreads();   // drains vmcnt (compiler) -> tiles visible

        s16x8 ah[FM], al[FM];
        #pragma unroll
        for (int fm = 0; fm < FM; fm++) {
            const int r = wm * (BM / 2) + fm * 16 + lr;
            const int d = r * 32 + ((lg ^ ((r >> 1) & 3)) << 3);
            ah[fm] = *(const s16x8*)&Ah[d];
            al[fm] = *(const s16x8*)&Al[d];
        }
        #pragma unroll
        for (int fn = 0; fn < 4; fn++) {
            const int r = wn * 64 + fn * 16 + lr;
            const int d = r * 32 + ((lg ^ ((r >> 1) & 3)) << 3);
            s16x8 bh = *(const s16x8*)&Bh[d];
            if constexpr (TERMS == 3) {
                s16x8 bl = *(const s16x8*)&Bl[d];
                #pragma unroll
                for (int fm = 0; fm < FM; fm++) {
                    acc[fm][fn] = __builtin_amdgcn_mfma_f32_16x16x32_bf16(ah[fm], bh, acc[fm][fn], 0, 0, 0);
                    acc[fm][fn] = __builtin_amdgcn_mfma_f32_16x16x32_bf16(ah[fm], bl, acc[fm][fn], 0, 0, 0);
                    acc[fm][fn] = __builtin_amdgcn_mfma_f32_16x16x32_bf16(al[fm], bh, acc[fm][fn], 0, 0, 0);
                }
            } else {
                #pragma unroll
                for (int fm = 0; fm < FM; fm++) {
                    acc[fm][fn] = __builtin_amdgcn_mfma_f32_16x16x32_bf16(ah[fm], bh, acc[fm][fn], 0, 0, 0);
                    acc[fm][fn] = __builtin_amdgcn_mfma_f32_16x16x32_bf16(al[fm], bh, acc[fm][fn], 0, 0, 0);
                }
            }
        }
    }
    // epilogue
    #pragma unroll
    for (int fm = 0; fm < FM; fm++)
        #pragma unroll
        for (int fn = 0; fn < 4; fn++)
            #pragma unroll
            for (int rg = 0; rg < 4; rg++) {
                const int r = m0 + wm * (BM / 2) + fm * 16 + lg * 4 + rg;
                const int c = n0 + wn * 64 + fn * 16 + lr;
                float v = acc[fm][fn][rg] + bias[c];
                if constexpr (EPI == 0) {
                    const int part = c >> 9, c2 = c & 511;
                    const int h = c2 & 7, dd = c2 >> 3;
                    const int b = r >> 10, n = r & 1023;
                    const size_t bh_ = (size_t)(b * 8 + h);
                    const size_t zo = (size_t)z * 2097152;
                    if (part == 0)      qq [zo + (bh_ * 1024 + n) * 64 + dd] = f2bf(v * QSCALE);
                    else if (part == 1) kkp[zo + (bh_ * 1024 + n) * 64 + dd] = f2bf(v);
                    else                vvp[zo + (bh_ * 64 + dd) * 1024 + n] = f2bf(v);
                } else {
                    float gl = v;
                    if constexpr (EPI == 1)
                        gl = 0.5f * v * (1.f + erff(v * 0.70710678118654752f));
                    u16 hv = f2bf(gl);
                    oh[(size_t)r * Ncols + c] = hv;
                    ol[(size_t)r * Ncols + c] = f2bf(gl - bf2f(hv));
                }
            }
}

// ---------------------------------------------------------------------------
// Flash attention, bf16 MFMA, z = layer (z==0 causal, z==1 anti-causal).
// K/Vt tiles staged in LDS via global_load_lds, double-buffered.
// ---------------------------------------------------------------------------
__global__ __launch_bounds__(256) void attn_mfma(const u16* __restrict__ Qg,
    const u16* __restrict__ Kg, const u16* __restrict__ Vtg,
    float* __restrict__ AO0, float* __restrict__ AO1)
{
    __shared__ u16 Ks[2][64 * 64];
    __shared__ u16 Vs[2][64 * 64];
    __shared__ u16 Ps[4][16 * 72];
    const int t = threadIdx.x, l = t & 63, w = t >> 6;
    const int lr = l & 15, lg = l >> 4;
    const int z = blockIdx.z;
    const int causal = (z == 0);
    const int bh = blockIdx.x;
    const int b = bh >> 3, h = bh & 7;
    const int qt = causal ? (15 - (int)blockIdx.y) : (int)blockIdx.y;  // long jobs first
    const u16* Qb = Qg + (size_t)(z * 32 + bh) * (NTOK * 64);
    const u16* Kb = Kg + (size_t)(z * 32 + bh) * (NTOK * 64);
    const u16* Vb = Vtg + (size_t)(z * 32 + bh) * (64 * NTOK);
    float* AO = z ? AO1 : AO0;
    const int q0 = qt * 64 + w * 16;

    s16x8 aq[2];
    aq[0] = *(const s16x8*)&Qb[(size_t)(q0 + lr) * 64 + lg * 8];
    aq[1] = *(const s16x8*)&Qb[(size_t)(q0 + lr) * 64 + 32 + lg * 8];

    f32x4 o[4];
    float m_[4], l_[4];
    #pragma unroll
    for (int f = 0; f < 4; f++) o[f] = f32x4{0.f, 0.f, 0.f, 0.f};
    #pragma unroll
    for (int r = 0; r < 4; r++) { m_[r] = -INFINITY; l_[r] = 0.f; }

    const int kt0 = causal ? 0 : qt, kt1 = causal ? qt : 15;

    auto stage = [&](int bufi, int kt) {
        #pragma unroll
        for (int i = 0; i < 2; i++) {
            const int j = w * 2 + i;
            const int r = j * 8 + (l >> 3);
            const int ck = (l & 7) ^ (r & 7);
            gll16(Kb + (size_t)(kt * 64 + r) * 64 + ck * 8, &Ks[bufi][j * 512]);
        }
        #pragma unroll
        for (int i = 0; i < 2; i++) {
            const int j = w * 2 + i;
            const int dim = j * 8 + (l >> 3);
            const int ck = (l & 7) ^ (dim & 7);
            gll16(Vb + (size_t)dim * NTOK + kt * 64 + ck * 8, &Vs[bufi][j * 512]);
        }
    };

    stage(0, kt0);
    __syncthreads();
    int buf = 0;
    for (int kt = kt0; kt <= kt1; kt++) {
        if (kt < kt1) stage(buf ^ 1, kt + 1);
        f32x4 s[4];
        #pragma unroll
        for (int f = 0; f < 4; f++) s[f] = f32x4{0.f, 0.f, 0.f, 0.f};
        #pragma unroll
        for (int kk = 0; kk < 2; kk++)
            #pragma unroll
            for (int f = 0; f < 4; f++) {
                const int row = f * 16 + lr;
                const int ch = kk * 4 + lg;
                s16x8 bk = *(const s16x8*)&Ks[buf][row * 64 + ((ch ^ (row & 7)) << 3)];
                s[f] = __builtin_amdgcn_mfma_f32_16x16x32_bf16(aq[kk], bk, s[f], 0, 0, 0);
            }
        if (kt == qt) {
            #pragma unroll
            for (int f = 0; f < 4; f++) {
                const int key = kt * 64 + f * 16 + lr;
                #pragma unroll
                for (int r = 0; r < 4; r++) {
                    const int q = q0 + lg * 4 + r;
                    if (causal ? (key > q) : (key < q)) s[f][r] = -INFINITY;
                }
            }
        }
        float scale[4];
        #pragma unroll
        for (int r = 0; r < 4; r++) {
            float rm = fmaxf(fmaxf(s[0][r], s[1][r]), fmaxf(s[2][r], s[3][r]));
            #pragma unroll
            for (int off = 1; off < 16; off <<= 1) rm = fmaxf(rm, __shfl_xor(rm, off));
            const float mn = fmaxf(m_[r], rm);
            scale[r] = __expf(m_[r] - mn);
            float ps = 0.f;
            #pragma unroll
            for (int f = 0; f < 4; f++) { float p = __expf(s[f][r] - mn); s[f][r] = p; ps += p; }
            #pragma unroll
            for (int off = 1; off < 16; off <<= 1) ps += __shfl_xor(ps, off);
            l_[r] = l_[r] * scale[r] + ps;
            m_[r] = mn;
        }
        #pragma unroll
        for (int f = 0; f < 4; f++)
            #pragma unroll
            for (int r = 0; r < 4; r++)
                Ps[w][(lg * 4 + r) * 72 + f * 16 + lr] = f2bf(s[f][r]);
        #pragma unroll
        for (int f = 0; f < 4; f++)
            #pragma unroll
            for (int r = 0; r < 4; r++) o[f][r] *= scale[r];
        #pragma unroll
        for (int kk = 0; kk < 2; kk++) {
            s16x8 ap = *(const s16x8*)&Ps[w][lr * 72 + kk * 32 + lg * 8];
            #pragma unroll
            for (int f = 0; f < 4; f++) {
                const int row = f * 16 + lr;
                const int ch = kk * 4 + lg;
                s16x8 bv = *(const s16x8*)&Vs[buf][row * 64 + ((ch ^ (row & 7)) << 3)];
                o[f] = __builtin_amdgcn_mfma_f32_16x16x32_bf16(ap, bv, o[f], 0, 0, 0);
            }
        }
        __syncthreads();
        buf ^= 1;
    }
    #pragma unroll
    for (int f = 0; f < 4; f++)
        #pragma unroll
        for (int r = 0; r < 4; r++)
            AO[(size_t)(b * NTOK + q0 + lg * 4 + r) * PL + h * 64 + f * 16 + lr] = o[f][r] / l_[r];
}

// ---------------------------------------------------------------------------
// add+LN A: x(f32)+attn(f32) -> LN -> hi/lo bf16. z = layer.
// ---------------------------------------------------------------------------
__global__ __launch_bounds__(256) void add_ln_a(const float* __restrict__ X,
    const float* __restrict__ A0, const float* __restrict__ A1,
    const float* __restrict__ g0, const float* __restrict__ g1,
    const float* __restrict__ be0, const float* __restrict__ be1,
    u16* __restrict__ OhiB, u16* __restrict__ OloB, const size_t oLS)
{
    const int z = blockIdx.z;
    const float* A = z ? A1 : A0;
    const float* g = z ? g1 : g0;
    const float* be = z ? be1 : be0;
    u16* Ohi = OhiB + (size_t)z * oLS;
    u16* Olo = OloB + (size_t)z * oLS;
    const int row = blockIdx.x * 4 + (threadIdx.x >> 6);
    const int lane = threadIdx.x & 63;
    const float* xr = X + (size_t)row * PL;
    const float* ar = A + (size_t)row * PL;
    float v[8];
    float sum = 0.f;
    #pragma unroll
    for (int u = 0; u < 8; u++) { v[u] = xr[lane + u * 64] + ar[lane + u * 64]; sum += v[u]; }
    #pragma unroll
    for (int o = 32; o > 0; o >>= 1) sum += __shfl_xor(sum, o);
    const float mu = sum * (1.f / 512.f);
    float s2 = 0.f;
    #pragma unroll
    for (int u = 0; u < 8; u++) { float d = v[u] - mu; s2 = fmaf(d, d, s2); }
    #pragma unroll
    for (int o = 32; o > 0; o >>= 1) s2 += __shfl_xor(s2, o);
    const float rstd = rsqrtf(s2 * (1.f / 512.f) + 1e-5f);
    #pragma unroll
    for (int u = 0; u < 8; u++) {
        const int c = lane + u * 64;
        float y = (v[u] - mu) * rstd * g[c] + be[c];
        u16 hv = f2bf(y);
        Ohi[(size_t)row * PL + c] = hv;
        Olo[(size_t)row * PL + c] = f2bf(y - bf2f(hv));
    }
}

// ---------------------------------------------------------------------------
// add+LN B: (x1 hi+lo) + (ff hi+lo) -> LN -> sigmoid -> bf16 td. z = layer.
// ---------------------------------------------------------------------------
__global__ __launch_bounds__(256) void add_ln_b(
    const u16* __restrict__ XhiB, const u16* __restrict__ XloB, const size_t xLS,
    const u16* __restrict__ F0h, const u16* __restrict__ F1h,
    const u16* __restrict__ F0l, const u16* __restrict__ F1l,
    const float* __restrict__ g0, const float* __restrict__ g1,
    const float* __restrict__ be0, const float* __restrict__ be1,
    u16* __restrict__ TD0, u16* __restrict__ TD1)
{
    const int z = blockIdx.z;
    const u16* Xhi = XhiB + (size_t)z * xLS;
    const u16* Xlo = XloB + (size_t)z * xLS;
    const u16* Fh = z ? F1h : F0h;
    const u16* Fl = z ? F1l : F0l;
    const float* g = z ? g1 : g0;
    const float* be = z ? be1 : be0;
    u16* TD = z ? TD1 : TD0;
    const int row = blockIdx.x * 4 + (threadIdx.x >> 6);
    const int lane = threadIdx.x & 63;
    const size_t ro = (size_t)row * PL;
    float v[8];
    float sum = 0.f;
    #pragma unroll
    for (int u = 0; u < 8; u++) {
        const int c = lane + u * 64;
        v[u] = bf2f(Xhi[ro + c]) + bf2f(Xlo[ro + c]) + bf2f(Fh[ro + c]) + bf2f(Fl[ro + c]);
        sum += v[u];
    }
    #pragma unroll
    for (int o = 32; o > 0; o >>= 1) sum += __shfl_xor(sum, o);
    const float mu = sum * (1.f / 512.f);
    float s2 = 0.f;
    #pragma unroll
    for (int u = 0; u < 8; u++) { float d = v[u] - mu; s2 = fmaf(d, d, s2); }
    #pragma unroll
    for (int o = 32; o > 0; o >>= 1) s2 += __shfl_xor(s2, o);
    const float rstd = rsqrtf(s2 * (1.f / 512.f) + 1e-5f);
    #pragma unroll
    for (int u = 0; u < 8; u++) {
        const int c = lane + u * 64;
        float y = (v[u] - mu) * rstd * g[c] + be[c];
        TD[ro + c] = f2bf(1.f / (1.f + expf(-y)));
    }
}

// ---------------------------------------------------------------------------
// sim: per batch, C[i][j] = dot(td1[i,:], td2[j,:]) / 512  (plain bf16 MFMA)
// gll-staged, BK=64.
// ---------------------------------------------------------------------------
__global__ __launch_bounds__(256) void sim_mfma(const u16* __restrict__ TD1,
    const u16* __restrict__ TD2, float* __restrict__ Out)
{
    __shared__ u16 Ah[128 * 64], Bh[128 * 64];
    const int t = threadIdx.x, l = t & 63, w = t >> 6;
    const int lr = l & 15, lg = l >> 4;
    const int wm = w >> 1, wn = w & 1;
    const int bz = blockIdx.z;
    const u16* A = TD1 + (size_t)bz * NTOK * PL;
    const u16* B = TD2 + (size_t)bz * NTOK * PL;
    const int m0 = blockIdx.x * 128, n0 = blockIdx.y * 128;

    f32x4 acc[4][4];
    #pragma unroll
    for (int i = 0; i < 4; i++)
        #pragma unroll
        for (int j = 0; j < 4; j++) acc[i][j] = f32x4{0.f, 0.f, 0.f, 0.f};

    for (int k0 = 0; k0 < 512; k0 += 64) {
        __syncthreads();
        #pragma unroll
        for (int i = 0; i < 4; i++) {
            const int j = w * 4 + i;
            const int r = j * 8 + (l >> 3);
            const int ck = (l & 7) ^ (r & 7);
            gll16(&A[(size_t)(m0 + r) * 512 + k0 + ck * 8], &Ah[j * 512]);
            gll16(&B[(size_t)(n0 + r) * 512 + k0 + ck * 8], &Bh[j * 512]);
        }
        __syncthreads();
        #pragma unroll
        for (int kk = 0; kk < 2; kk++) {
            const int ch = kk * 4 + lg;
            s16x8 af[4], bf[4];
            #pragma unroll
            for (int fm = 0; fm < 4; fm++) {
                const int r = wm * 64 + fm * 16 + lr;
                af[fm] = *(const s16x8*)&Ah[r * 64 + ((ch ^ (r & 7)) << 3)];
            }
            #pragma unroll
            for (int fn = 0; fn < 4; fn++) {
                const int r = wn * 64 + fn * 16 + lr;
                bf[fn] = *(const s16x8*)&Bh[r * 64 + ((ch ^ (r & 7)) << 3)];
            }
            #pragma unroll
            for (int fm = 0; fm < 4; fm++)
                #pragma unroll
                for (int fn = 0; fn < 4; fn++)
                    acc[fm][fn] = __builtin_amdgcn_mfma_f32_16x16x32_bf16(af[fm], bf[fn], acc[fm][fn], 0, 0, 0);
        }
    }
    #pragma unroll
    for (int fm = 0; fm < 4; fm++)
        #pragma unroll
        for (int fn = 0; fn < 4; fn++)
            #pragma unroll
            for (int rg = 0; rg < 4; rg++) {
                const int r = m0 + wm * 64 + fm * 16 + lg * 4 + rg;
                const int c = n0 + wn * 64 + fn * 16 + lr;
                Out[((size_t)(bz * NTOK + r)) * NTOK + c] = acc[fm][fn][rg] * (1.f / 512.f);
            }
}

// ---------------------------------------------------------------------------
extern "C" void kernel_launch(void* const* d_in, const int* in_sizes, int n_in,
                              void* d_out, int out_size, void* d_ws, size_t ws_size,
                              hipStream_t stream)
{
    const float* x = (const float*)d_in[0];
    const float* wqkv[2] = {(const float*)d_in[1],  (const float*)d_in[11]};
    const float* bqkv[2] = {(const float*)d_in[2],  (const float*)d_in[12]};
    const float* ga[2]   = {(const float*)d_in[3],  (const float*)d_in[13]};
    const float* bea[2]  = {(const float*)d_in[4],  (const float*)d_in[14]};
    const float* w1[2]   = {(const float*)d_in[5],  (const float*)d_in[15]};
    const float* b1[2]   = {(const float*)d_in[6],  (const float*)d_in[16]};
    const float* w2[2]   = {(const float*)d_in[7],  (const float*)d_in[17]};
    const float* b2[2]   = {(const float*)d_in[8],  (const float*)d_in[18]};
    const float* gb[2]   = {(const float*)d_in[9],  (const float*)d_in[19]};
    const float* beb[2]  = {(const float*)d_in[10], (const float*)d_in[20]};

    // -------- workspace map (KB offsets; lifetimes verified stage-by-stage) --
    char* wsb = (char*)d_ws;
    char* ob  = (char*)d_out;
    #define WSK(kb) ((char*)wsb + ((size_t)(kb) << 10))
    #define OBK(kb) ((char*)ob  + ((size_t)(kb) << 10))
    // ws: [0,4M) wff (S1-S6) -> td1 (S7-)
    u16* w1h = (u16*)WSK(0);      // + z*1048576 elems  (lo unused for FF now)
    u16* w1l = (u16*)WSK(512);
    u16* w2h = (u16*)WSK(1024);
    u16* w2l = (u16*)WSK(1536);
    u16* td1 = (u16*)WSK(0);
    // ws: [4M,12M) xsplit (S0-S2) -> AO0 f32 (S3-S4) -> ffo0 hi/lo (S6-S7)
    u16*   xhi  = (u16*)WSK(4096);
    u16*   xlo  = (u16*)WSK(8192);
    float* AO0  = (float*)WSK(4096);
    u16*   ffo0h = (u16*)WSK(4096);
    u16*   ffo0l = (u16*)WSK(8192);
    // ws: [12M,18M) wq (S1-S2); [12M,16M) ffo1hi (S6-S7)
    u16* wqh = (u16*)WSK(12288);  // + z*786432 elems
    u16* wql = (u16*)WSK(13824);
    u16* ffo1h = (u16*)WSK(12288);
    // ws: [16M,32M) x1 hi/lo (S4-S7)
    u16* x1h = (u16*)WSK(16384);  // + z*4194304 elems
    u16* x1l = (u16*)WSK(20480);
    // ws: [18M,34M) Q,K (S2-S3)
    u16* Qb = (u16*)WSK(18432);   // + z*2097152 elems
    u16* Kb = (u16*)WSK(26624);
    // ws: [32M,36M) ffo1lo (S6-S7); [36M,40M) td2 (S7-)
    u16* ffo1l = (u16*)WSK(32768);
    u16* td2   = (u16*)WSK(36864);
    // d_out: Vt (S2-S3); AO1 (S3-S4); h hi/lo (S5-S6); final out (S8)
    u16*   Vt  = (u16*)OBK(0);    // + z*2097152 elems
    float* AO1 = (float*)OBK(8192);
    u16*   h0h = (u16*)OBK(0);
    u16*   h0l = (u16*)OBK(4096);
    u16*   h1h = (u16*)OBK(8192);
    u16*   h1l = (u16*)OBK(12288);
    float* out = (float*)d_out;

    // S0: x split
    convert_x<<<2048, 256, 0, stream>>>(x, xhi, xlo);
    // S1: weight transposes+splits (z = layer); FF weights: hi only (2-term)
    convert_wt<<<dim3(16, 48, 2), 256, 0, stream>>>(wqkv[0], wqkv[1], wqh, wql, 786432, 1536, 1);
    convert_wt<<<dim3(16, 16, 2), 256, 0, stream>>>(w1[0], w1[1], w1h, nullptr, 1048576, 512, 0);
    convert_wt<<<dim3(16, 16, 2), 256, 0, stream>>>(w2[0], w2[1], w2h, nullptr, 1048576, 512, 0);
    // S2: qkv gemm (both layers), 3-term
    gemm_split<128, 3, 0><<<dim3(32, 12, 2), 256, 0, stream>>>(
        xhi, xlo, 0, wqh, wql, 786432, bqkv[0], bqkv[1], 1536,
        Qb, Kb, Vt, nullptr, nullptr, nullptr, nullptr);
    // S3: attention (both layers; z=0 causal, z=1 anti-causal)
    attn_mfma<<<dim3(32, 16, 2), 256, 0, stream>>>(Qb, Kb, Vt, AO0, AO1);
    // S4: add + LN -> x1 hi/lo
    add_ln_a<<<dim3(1024, 1, 2), 256, 0, stream>>>(x, AO0, AO1,
        ga[0], ga[1], bea[0], bea[1], x1h, x1l, 4194304);
    // S5: ff1 (gelu) -> h hi/lo (in d_out), 2-term
    gemm_split<64, 2, 1><<<dim3(64, 4, 2), 256, 0, stream>>>(
        x1h, x1l, 4194304, w1h, nullptr, 1048576, b1[0], b1[1], 512,
        nullptr, nullptr, nullptr, h0h, h1h, h0l, h1l);
    // S6: ff2 -> ffo hi/lo (in ws), 2-term
    gemm_split<64, 2, 2><<<dim3(64, 4, 2), 256, 0, stream>>>(
        h0h, h0l, 4194304, w2h, nullptr, 1048576, b2[0], b2[1], 512,
        nullptr, nullptr, nullptr, ffo0h, ffo1h, ffo0l, ffo1l);
    // S7: add + LN + sigmoid -> td
    add_ln_b<<<dim3(1024, 1, 2), 256, 0, stream>>>(
        x1h, x1l, 4194304, ffo0h, ffo1h, ffo0l, ffo1l,
        gb[0], gb[1], beb[0], beb[1], td1, td2);
    // S8: sim
    sim_mfma<<<dim3(8, 8, 4), 256, 0, stream>>>(td1, td2, out);
}

// Round 7
// 181.274 us; speedup vs baseline: 12.5767x; 1.0660x over previous
//
#include <hip/hip_runtime.h>
#include <math.h>

// ---------------------------------------------------------------------------
// bf16-MFMA implementation, both layers merged (z=2), global_load_lds staging.
//  - qkv GEMM: 2-term (x hi/lo × w-hi) — score-path error ≤~3e-4, proven path
//  - ff1/ff2:  2-term (A hi/lo, B hi)  — R5-proven
//  - attention + sim: plain bf16 MFMA
//  - BK=32 GEMM tiles, swizzle ch ^= (row>>1)&3 (R5-proven, 0 conflicts)
// ---------------------------------------------------------------------------

typedef float f32x4 __attribute__((ext_vector_type(4)));
typedef short s16x8 __attribute__((ext_vector_type(8)));
typedef unsigned short u16;
typedef unsigned int u32;

#define NTOK 1024
#define PL 512
#define QSCALE 0.04419417382415922f  // 1/sqrt(512)

__device__ inline u16 f2bf(float f) {
    unsigned u = __builtin_bit_cast(unsigned, f);
    unsigned r = u + 0x7fffu + ((u >> 16) & 1u);   // RNE
    return (u16)(r >> 16);
}
__device__ inline float bf2f(u16 h) {
    unsigned u = ((unsigned)h) << 16;
    return __builtin_bit_cast(float, u);
}

__device__ inline void gll16(const void* g, void* l) {
    __builtin_amdgcn_global_load_lds(
        (const __attribute__((address_space(1))) u32*)g,
        (__attribute__((address_space(3))) u32*)l, 16, 0, 0);
}

// ---------------------------------------------------------------------------
// x -> hi/lo bf16 split (elementwise)
// ---------------------------------------------------------------------------
__global__ __launch_bounds__(256) void convert_x(const float* __restrict__ X,
    u16* __restrict__ hi, u16* __restrict__ lo)
{
    const int i = (blockIdx.x * 256 + threadIdx.x) * 4;
    float4 v = *(const float4*)&X[i];
    float vv[4] = {v.x, v.y, v.z, v.w};
    #pragma unroll
    for (int j = 0; j < 4; j++) {
        u16 h = f2bf(vv[j]);
        hi[i + j] = h;
        lo[i + j] = f2bf(vv[j] - bf2f(h));
    }
}

// ---------------------------------------------------------------------------
// W [512][N] f32 -> Wt [N][512] bf16 hi(/lo) (tiled transpose), z = layer
// ---------------------------------------------------------------------------
__global__ __launch_bounds__(256) void convert_wt(const float* __restrict__ W0,
    const float* __restrict__ W1, u16* __restrict__ WhiB, u16* __restrict__ WloB,
    const size_t dLS, const int N, const int writeLo)
{
    const float* W = blockIdx.z ? W1 : W0;
    u16* Whi = WhiB + (size_t)blockIdx.z * dLS;
    u16* Wlo = WloB ? (WloB + (size_t)blockIdx.z * dLS) : nullptr;
    __shared__ float T[32][36];
    const int k0 = blockIdx.x * 32, n0 = blockIdx.y * 32;
    const int tr = threadIdx.x >> 3, tc = (threadIdx.x & 7) * 4;
    *(float4*)&T[tr][tc] = *(const float4*)&W[(size_t)(k0 + tr) * N + n0 + tc];
    __syncthreads();
    u16 hv[4], lv[4];
    #pragma unroll
    for (int j = 0; j < 4; j++) {
        float v = T[tc + j][tr];
        hv[j] = f2bf(v);
        lv[j] = f2bf(v - bf2f(hv[j]));
    }
    const size_t o = (size_t)(n0 + tr) * 512 + k0 + tc;
    #pragma unroll
    for (int j = 0; j < 4; j++) Whi[o + j] = hv[j];
    if (writeLo)
        #pragma unroll
        for (int j = 0; j < 4; j++) Wlo[o + j] = lv[j];
}

// ---------------------------------------------------------------------------
// Split-bf16 MFMA GEMM, z = layer. A[4096][512] (hi/lo) x Bt[N][512].
// TERMS: 3 = ah*bh+ah*bl+al*bh, 2 = ah*bh+al*bh (B single bf16).
// EPI: 0 = qkv scatter (Q scaled, K, Vt), 1 = gelu -> hi/lo, 2 = plain hi/lo.
// BK=32; staging via global_load_lds (linear dest, pre-swizzled source).
// ---------------------------------------------------------------------------
template<int BM, int TERMS, int EPI>
__global__ __launch_bounds__(256) void gemm_split(
    const u16* __restrict__ AhiB, const u16* __restrict__ AloB, const size_t aLS,
    const u16* __restrict__ BhiB, const u16* __restrict__ BloB, const size_t bLS,
    const float* __restrict__ bias0, const float* __restrict__ bias1, const int Ncols,
    u16* __restrict__ qq, u16* __restrict__ kkp, u16* __restrict__ vvp,
    u16* __restrict__ oh0, u16* __restrict__ oh1,
    u16* __restrict__ ol0, u16* __restrict__ ol1)
{
    constexpr int FM = BM / 32;
    __shared__ u16 Ah[BM * 32], Al[BM * 32], Bh[128 * 32];
    __shared__ u16 Bl[(TERMS == 3) ? 128 * 32 : 64];
    const int z = blockIdx.z;
    const u16* Ahi = AhiB + (size_t)z * aLS;
    const u16* Alo = AloB + (size_t)z * aLS;
    const u16* Bhi = BhiB + (size_t)z * bLS;
    const u16* Blo = BloB ? (BloB + (size_t)z * bLS) : nullptr;
    const float* bias = z ? bias1 : bias0;
    u16* oh = z ? oh1 : oh0;
    u16* ol = z ? ol1 : ol0;

    const int t = threadIdx.x, l = t & 63, w = t >> 6;
    const int lr = l & 15, lg = l >> 4;
    const int wm = w >> 1, wn = w & 1;
    const int m0 = blockIdx.x * BM, n0 = blockIdx.y * 128;
    const int srow = l >> 2, sch = l & 3;    // staging lane coords (16 rows/KB)

    f32x4 acc[FM][4];
    #pragma unroll
    for (int i = 0; i < FM; i++)
        #pragma unroll
        for (int j = 0; j < 4; j++) acc[i][j] = f32x4{0.f, 0.f, 0.f, 0.f};

    for (int k0 = 0; k0 < 512; k0 += 32) {
        __syncthreads();
        #pragma unroll
        for (int i = 0; i < BM / 64; i++) {
            const int j = w * (BM / 64) + i;
            const int r = j * 16 + srow;
            const int ck = sch ^ ((r >> 1) & 3);
            const size_t g = (size_t)(m0 + r) * 512 + k0 + ck * 8;
            gll16(&Ahi[g], &Ah[j * 512]);
            gll16(&Alo[g], &Al[j * 512]);
        }
        #pragma unroll
        for (int i = 0; i < 2; i++) {
            const int j = w * 2 + i;
            const int r = j * 16 + srow;
            const int ck = sch ^ ((r >> 1) & 3);
            const size_t g = (size_t)(n0 + r) * 512 + k0 + ck * 8;
            gll16(&Bhi[g], &Bh[j * 512]);
            if constexpr (TERMS == 3) gll16(&Blo[g], &Bl[j * 512]);
        }
        __syncthreads();   // drains vmcnt (compiler) -> tiles visible

        s16x8 ah[FM], al[FM];
        #pragma unroll
        for (int fm = 0; fm < FM; fm++) {
            const int r = wm * (BM / 2) + fm * 16 + lr;
            const int d = r * 32 + ((lg ^ ((r >> 1) & 3)) << 3);
            ah[fm] = *(const s16x8*)&Ah[d];
            al[fm] = *(const s16x8*)&Al[d];
        }
        #pragma unroll
        for (int fn = 0; fn < 4; fn++) {
            const int r = wn * 64 + fn * 16 + lr;
            const int d = r * 32 + ((lg ^ ((r >> 1) & 3)) << 3);
            s16x8 bh = *(const s16x8*)&Bh[d];
            if constexpr (TERMS == 3) {
                s16x8 bl = *(const s16x8*)&Bl[d];
                #pragma unroll
                for (int fm = 0; fm < FM; fm++) {
                    acc[fm][fn] = __builtin_amdgcn_mfma_f32_16x16x32_bf16(ah[fm], bh, acc[fm][fn], 0, 0, 0);
                    acc[fm][fn] = __builtin_amdgcn_mfma_f32_16x16x32_bf16(ah[fm], bl, acc[fm][fn], 0, 0, 0);
                    acc[fm][fn] = __builtin_amdgcn_mfma_f32_16x16x32_bf16(al[fm], bh, acc[fm][fn], 0, 0, 0);
                }
            } else {
                #pragma unroll
                for (int fm = 0; fm < FM; fm++) {
                    acc[fm][fn] = __builtin_amdgcn_mfma_f32_16x16x32_bf16(ah[fm], bh, acc[fm][fn], 0, 0, 0);
                    acc[fm][fn] = __builtin_amdgcn_mfma_f32_16x16x32_bf16(al[fm], bh, acc[fm][fn], 0, 0, 0);
                }
            }
        }
    }
    // epilogue
    #pragma unroll
    for (int fm = 0; fm < FM; fm++)
        #pragma unroll
        for (int fn = 0; fn < 4; fn++)
            #pragma unroll
            for (int rg = 0; rg < 4; rg++) {
                const int r = m0 + wm * (BM / 2) + fm * 16 + lg * 4 + rg;
                const int c = n0 + wn * 64 + fn * 16 + lr;
                float v = acc[fm][fn][rg] + bias[c];
                if constexpr (EPI == 0) {
                    const int part = c >> 9, c2 = c & 511;
                    const int h = c2 & 7, dd = c2 >> 3;
                    const int b = r >> 10, n = r & 1023;
                    const size_t bh_ = (size_t)(b * 8 + h);
                    const size_t zo = (size_t)z * 2097152;
                    if (part == 0)      qq [zo + (bh_ * 1024 + n) * 64 + dd] = f2bf(v * QSCALE);
                    else if (part == 1) kkp[zo + (bh_ * 1024 + n) * 64 + dd] = f2bf(v);
                    else                vvp[zo + (bh_ * 64 + dd) * 1024 + n] = f2bf(v);
                } else {
                    float gl = v;
                    if constexpr (EPI == 1)
                        gl = 0.5f * v * (1.f + erff(v * 0.70710678118654752f));
                    u16 hv = f2bf(gl);
                    oh[(size_t)r * Ncols + c] = hv;
                    ol[(size_t)r * Ncols + c] = f2bf(gl - bf2f(hv));
                }
            }
}

// ---------------------------------------------------------------------------
// Flash attention, bf16 MFMA, z = layer (z==0 causal, z==1 anti-causal).
// K/Vt tiles staged in LDS via global_load_lds, double-buffered.
// ---------------------------------------------------------------------------
__global__ __launch_bounds__(256) void attn_mfma(const u16* __restrict__ Qg,
    const u16* __restrict__ Kg, const u16* __restrict__ Vtg,
    float* __restrict__ AO0, float* __restrict__ AO1)
{
    __shared__ u16 Ks[2][64 * 64];
    __shared__ u16 Vs[2][64 * 64];
    __shared__ u16 Ps[4][16 * 72];
    const int t = threadIdx.x, l = t & 63, w = t >> 6;
    const int lr = l & 15, lg = l >> 4;
    const int z = blockIdx.z;
    const int causal = (z == 0);
    const int bh = blockIdx.x;
    const int b = bh >> 3, h = bh & 7;
    const int qt = causal ? (15 - (int)blockIdx.y) : (int)blockIdx.y;  // long jobs first
    const u16* Qb = Qg + (size_t)(z * 32 + bh) * (NTOK * 64);
    const u16* Kb = Kg + (size_t)(z * 32 + bh) * (NTOK * 64);
    const u16* Vb = Vtg + (size_t)(z * 32 + bh) * (64 * NTOK);
    float* AO = z ? AO1 : AO0;
    const int q0 = qt * 64 + w * 16;

    s16x8 aq[2];
    aq[0] = *(const s16x8*)&Qb[(size_t)(q0 + lr) * 64 + lg * 8];
    aq[1] = *(const s16x8*)&Qb[(size_t)(q0 + lr) * 64 + 32 + lg * 8];

    f32x4 o[4];
    float m_[4], l_[4];
    #pragma unroll
    for (int f = 0; f < 4; f++) o[f] = f32x4{0.f, 0.f, 0.f, 0.f};
    #pragma unroll
    for (int r = 0; r < 4; r++) { m_[r] = -INFINITY; l_[r] = 0.f; }

    const int kt0 = causal ? 0 : qt, kt1 = causal ? qt : 15;

    auto stage = [&](int bufi, int kt) {
        #pragma unroll
        for (int i = 0; i < 2; i++) {
            const int j = w * 2 + i;
            const int r = j * 8 + (l >> 3);
            const int ck = (l & 7) ^ (r & 7);
            gll16(Kb + (size_t)(kt * 64 + r) * 64 + ck * 8, &Ks[bufi][j * 512]);
        }
        #pragma unroll
        for (int i = 0; i < 2; i++) {
            const int j = w * 2 + i;
            const int dim = j * 8 + (l >> 3);
            const int ck = (l & 7) ^ (dim & 7);
            gll16(Vb + (size_t)dim * NTOK + kt * 64 + ck * 8, &Vs[bufi][j * 512]);
        }
    };

    stage(0, kt0);
    __syncthreads();
    int buf = 0;
    for (int kt = kt0; kt <= kt1; kt++) {
        if (kt < kt1) stage(buf ^ 1, kt + 1);
        f32x4 s[4];
        #pragma unroll
        for (int f = 0; f < 4; f++) s[f] = f32x4{0.f, 0.f, 0.f, 0.f};
        #pragma unroll
        for (int kk = 0; kk < 2; kk++)
            #pragma unroll
            for (int f = 0; f < 4; f++) {
                const int row = f * 16 + lr;
                const int ch = kk * 4 + lg;
                s16x8 bk = *(const s16x8*)&Ks[buf][row * 64 + ((ch ^ (row & 7)) << 3)];
                s[f] = __builtin_amdgcn_mfma_f32_16x16x32_bf16(aq[kk], bk, s[f], 0, 0, 0);
            }
        if (kt == qt) {
            #pragma unroll
            for (int f = 0; f < 4; f++) {
                const int key = kt * 64 + f * 16 + lr;
                #pragma unroll
                for (int r = 0; r < 4; r++) {
                    const int q = q0 + lg * 4 + r;
                    if (causal ? (key > q) : (key < q)) s[f][r] = -INFINITY;
                }
            }
        }
        float scale[4];
        #pragma unroll
        for (int r = 0; r < 4; r++) {
            float rm = fmaxf(fmaxf(s[0][r], s[1][r]), fmaxf(s[2][r], s[3][r]));
            #pragma unroll
            for (int off = 1; off < 16; off <<= 1) rm = fmaxf(rm, __shfl_xor(rm, off));
            const float mn = fmaxf(m_[r], rm);
            scale[r] = __expf(m_[r] - mn);
            float ps = 0.f;
            #pragma unroll
            for (int f = 0; f < 4; f++) { float p = __expf(s[f][r] - mn); s[f][r] = p; ps += p; }
            #pragma unroll
            for (int off = 1; off < 16; off <<= 1) ps += __shfl_xor(ps, off);
            l_[r] = l_[r] * scale[r] + ps;
            m_[r] = mn;
        }
        #pragma unroll
        for (int f = 0; f < 4; f++)
            #pragma unroll
            for (int r = 0; r < 4; r++)
                Ps[w][(lg * 4 + r) * 72 + f * 16 + lr] = f2bf(s[f][r]);
        #pragma unroll
        for (int f = 0; f < 4; f++)
            #pragma unroll
            for (int r = 0; r < 4; r++) o[f][r] *= scale[r];
        #pragma unroll
        for (int kk = 0; kk < 2; kk++) {
            s16x8 ap = *(const s16x8*)&Ps[w][lr * 72 + kk * 32 + lg * 8];
            #pragma unroll
            for (int f = 0; f < 4; f++) {
                const int row = f * 16 + lr;
                const int ch = kk * 4 + lg;
                s16x8 bv = *(const s16x8*)&Vs[buf][row * 64 + ((ch ^ (row & 7)) << 3)];
                o[f] = __builtin_amdgcn_mfma_f32_16x16x32_bf16(ap, bv, o[f], 0, 0, 0);
            }
        }
        __syncthreads();
        buf ^= 1;
    }
    #pragma unroll
    for (int f = 0; f < 4; f++)
        #pragma unroll
        for (int r = 0; r < 4; r++)
            AO[(size_t)(b * NTOK + q0 + lg * 4 + r) * PL + h * 64 + f * 16 + lr] = o[f][r] / l_[r];
}

// ---------------------------------------------------------------------------
// add+LN A: x(f32)+attn(f32) -> LN -> hi/lo bf16. z = layer.
// ---------------------------------------------------------------------------
__global__ __launch_bounds__(256) void add_ln_a(const float* __restrict__ X,
    const float* __restrict__ A0, const float* __restrict__ A1,
    const float* __restrict__ g0, const float* __restrict__ g1,
    const float* __restrict__ be0, const float* __restrict__ be1,
    u16* __restrict__ OhiB, u16* __restrict__ OloB, const size_t oLS)
{
    const int z = blockIdx.z;
    const float* A = z ? A1 : A0;
    const float* g = z ? g1 : g0;
    const float* be = z ? be1 : be0;
    u16* Ohi = OhiB + (size_t)z * oLS;
    u16* Olo = OloB + (size_t)z * oLS;
    const int row = blockIdx.x * 4 + (threadIdx.x >> 6);
    const int lane = threadIdx.x & 63;
    const float* xr = X + (size_t)row * PL;
    const float* ar = A + (size_t)row * PL;
    float v[8];
    float sum = 0.f;
    #pragma unroll
    for (int u = 0; u < 8; u++) { v[u] = xr[lane + u * 64] + ar[lane + u * 64]; sum += v[u]; }
    #pragma unroll
    for (int o = 32; o > 0; o >>= 1) sum += __shfl_xor(sum, o);
    const float mu = sum * (1.f / 512.f);
    float s2 = 0.f;
    #pragma unroll
    for (int u = 0; u < 8; u++) { float d = v[u] - mu; s2 = fmaf(d, d, s2); }
    #pragma unroll
    for (int o = 32; o > 0; o >>= 1) s2 += __shfl_xor(s2, o);
    const float rstd = rsqrtf(s2 * (1.f / 512.f) + 1e-5f);
    #pragma unroll
    for (int u = 0; u < 8; u++) {
        const int c = lane + u * 64;
        float y = (v[u] - mu) * rstd * g[c] + be[c];
        u16 hv = f2bf(y);
        Ohi[(size_t)row * PL + c] = hv;
        Olo[(size_t)row * PL + c] = f2bf(y - bf2f(hv));
    }
}

// ---------------------------------------------------------------------------
// add+LN B: (x1 hi+lo) + (ff hi+lo) -> LN -> sigmoid -> bf16 td. z = layer.
// ---------------------------------------------------------------------------
__global__ __launch_bounds__(256) void add_ln_b(
    const u16* __restrict__ XhiB, const u16* __restrict__ XloB, const size_t xLS,
    const u16* __restrict__ F0h, const u16* __restrict__ F1h,
    const u16* __restrict__ F0l, const u16* __restrict__ F1l,
    const float* __restrict__ g0, const float* __restrict__ g1,
    const float* __restrict__ be0, const float* __restrict__ be1,
    u16* __restrict__ TD0, u16* __restrict__ TD1)
{
    const int z = blockIdx.z;
    const u16* Xhi = XhiB + (size_t)z * xLS;
    const u16* Xlo = XloB + (size_t)z * xLS;
    const u16* Fh = z ? F1h : F0h;
    const u16* Fl = z ? F1l : F0l;
    const float* g = z ? g1 : g0;
    const float* be = z ? be1 : be0;
    u16* TD = z ? TD1 : TD0;
    const int row = blockIdx.x * 4 + (threadIdx.x >> 6);
    const int lane = threadIdx.x & 63;
    const size_t ro = (size_t)row * PL;
    float v[8];
    float sum = 0.f;
    #pragma unroll
    for (int u = 0; u < 8; u++) {
        const int c = lane + u * 64;
        v[u] = bf2f(Xhi[ro + c]) + bf2f(Xlo[ro + c]) + bf2f(Fh[ro + c]) + bf2f(Fl[ro + c]);
        sum += v[u];
    }
    #pragma unroll
    for (int o = 32; o > 0; o >>= 1) sum += __shfl_xor(sum, o);
    const float mu = sum * (1.f / 512.f);
    float s2 = 0.f;
    #pragma unroll
    for (int u = 0; u < 8; u++) { float d = v[u] - mu; s2 = fmaf(d, d, s2); }
    #pragma unroll
    for (int o = 32; o > 0; o >>= 1) s2 += __shfl_xor(s2, o);
    const float rstd = rsqrtf(s2 * (1.f / 512.f) + 1e-5f);
    #pragma unroll
    for (int u = 0; u < 8; u++) {
        const int c = lane + u * 64;
        float y = (v[u] - mu) * rstd * g[c] + be[c];
        TD[ro + c] = f2bf(1.f / (1.f + expf(-y)));
    }
}

// ---------------------------------------------------------------------------
// sim: per batch, C[i][j] = dot(td1[i,:], td2[j,:]) / 512  (plain bf16 MFMA)
// gll-staged, BK=64.
// ---------------------------------------------------------------------------
__global__ __launch_bounds__(256) void sim_mfma(const u16* __restrict__ TD1,
    const u16* __restrict__ TD2, float* __restrict__ Out)
{
    __shared__ u16 Ah[128 * 64], Bh[128 * 64];
    const int t = threadIdx.x, l = t & 63, w = t >> 6;
    const int lr = l & 15, lg = l >> 4;
    const int wm = w >> 1, wn = w & 1;
    const int bz = blockIdx.z;
    const u16* A = TD1 + (size_t)bz * NTOK * PL;
    const u16* B = TD2 + (size_t)bz * NTOK * PL;
    const int m0 = blockIdx.x * 128, n0 = blockIdx.y * 128;

    f32x4 acc[4][4];
    #pragma unroll
    for (int i = 0; i < 4; i++)
        #pragma unroll
        for (int j = 0; j < 4; j++) acc[i][j] = f32x4{0.f, 0.f, 0.f, 0.f};

    for (int k0 = 0; k0 < 512; k0 += 64) {
        __syncthreads();
        #pragma unroll
        for (int i = 0; i < 4; i++) {
            const int j = w * 4 + i;
            const int r = j * 8 + (l >> 3);
            const int ck = (l & 7) ^ (r & 7);
            gll16(&A[(size_t)(m0 + r) * 512 + k0 + ck * 8], &Ah[j * 512]);
            gll16(&B[(size_t)(n0 + r) * 512 + k0 + ck * 8], &Bh[j * 512]);
        }
        __syncthreads();
        #pragma unroll
        for (int kk = 0; kk < 2; kk++) {
            const int ch = kk * 4 + lg;
            s16x8 af[4], bf[4];
            #pragma unroll
            for (int fm = 0; fm < 4; fm++) {
                const int r = wm * 64 + fm * 16 + lr;
                af[fm] = *(const s16x8*)&Ah[r * 64 + ((ch ^ (r & 7)) << 3)];
            }
            #pragma unroll
            for (int fn = 0; fn < 4; fn++) {
                const int r = wn * 64 + fn * 16 + lr;
                bf[fn] = *(const s16x8*)&Bh[r * 64 + ((ch ^ (r & 7)) << 3)];
            }
            #pragma unroll
            for (int fm = 0; fm < 4; fm++)
                #pragma unroll
                for (int fn = 0; fn < 4; fn++)
                    acc[fm][fn] = __builtin_amdgcn_mfma_f32_16x16x32_bf16(af[fm], bf[fn], acc[fm][fn], 0, 0, 0);
        }
    }
    #pragma unroll
    for (int fm = 0; fm < 4; fm++)
        #pragma unroll
        for (int fn = 0; fn < 4; fn++)
            #pragma unroll
            for (int rg = 0; rg < 4; rg++) {
                const int r = m0 + wm * 64 + fm * 16 + lg * 4 + rg;
                const int c = n0 + wn * 64 + fn * 16 + lr;
                Out[((size_t)(bz * NTOK + r)) * NTOK + c] = acc[fm][fn][rg] * (1.f / 512.f);
            }
}

// ---------------------------------------------------------------------------
extern "C" void kernel_launch(void* const* d_in, const int* in_sizes, int n_in,
                              void* d_out, int out_size, void* d_ws, size_t ws_size,
                              hipStream_t stream)
{
    const float* x = (const float*)d_in[0];
    const float* wqkv[2] = {(const float*)d_in[1],  (const float*)d_in[11]};
    const float* bqkv[2] = {(const float*)d_in[2],  (const float*)d_in[12]};
    const float* ga[2]   = {(const float*)d_in[3],  (const float*)d_in[13]};
    const float* bea[2]  = {(const float*)d_in[4],  (const float*)d_in[14]};
    const float* w1[2]   = {(const float*)d_in[5],  (const float*)d_in[15]};
    const float* b1[2]   = {(const float*)d_in[6],  (const float*)d_in[16]};
    const float* w2[2]   = {(const float*)d_in[7],  (const float*)d_in[17]};
    const float* b2[2]   = {(const float*)d_in[8],  (const float*)d_in[18]};
    const float* gb[2]   = {(const float*)d_in[9],  (const float*)d_in[19]};
    const float* beb[2]  = {(const float*)d_in[10], (const float*)d_in[20]};

    // -------- workspace map (KB offsets; identical to R5's proven layout) --
    char* wsb = (char*)d_ws;
    char* ob  = (char*)d_out;
    #define WSK(kb) ((char*)wsb + ((size_t)(kb) << 10))
    #define OBK(kb) ((char*)ob  + ((size_t)(kb) << 10))
    // ws: [0,4M) wff (S1-S6) -> td1 (S7-)
    u16* w1h = (u16*)WSK(0);      // + z*1048576 elems  (lo unused for FF)
    u16* w1l = (u16*)WSK(512);
    u16* w2h = (u16*)WSK(1024);
    u16* w2l = (u16*)WSK(1536);
    u16* td1 = (u16*)WSK(0);
    // ws: [4M,12M) xsplit (S0-S2) -> AO0 f32 (S3-S4) -> ffo0 hi/lo (S6-S7)
    u16*   xhi  = (u16*)WSK(4096);
    u16*   xlo  = (u16*)WSK(8192);
    float* AO0  = (float*)WSK(4096);
    u16*   ffo0h = (u16*)WSK(4096);
    u16*   ffo0l = (u16*)WSK(8192);
    // ws: [12M,18M) wq hi (S1-S2); [12M,16M) ffo1hi (S6-S7)
    u16* wqh = (u16*)WSK(12288);  // + z*786432 elems
    u16* ffo1h = (u16*)WSK(12288);
    // ws: [16M,32M) x1 hi/lo (S4-S7)
    u16* x1h = (u16*)WSK(16384);  // + z*4194304 elems
    u16* x1l = (u16*)WSK(20480);
    // ws: [18M,34M) Q,K (S2-S3)
    u16* Qb = (u16*)WSK(18432);   // + z*2097152 elems
    u16* Kb = (u16*)WSK(26624);
    // ws: [32M,36M) ffo1lo (S6-S7); [36M,40M) td2 (S7-)
    u16* ffo1l = (u16*)WSK(32768);
    u16* td2   = (u16*)WSK(36864);
    // d_out: Vt (S2-S3); AO1 (S3-S4); h hi/lo (S5-S6); final out (S8)
    u16*   Vt  = (u16*)OBK(0);    // + z*2097152 elems
    float* AO1 = (float*)OBK(8192);
    u16*   h0h = (u16*)OBK(0);
    u16*   h0l = (u16*)OBK(4096);
    u16*   h1h = (u16*)OBK(8192);
    u16*   h1l = (u16*)OBK(12288);
    float* out = (float*)d_out;

    // S0: x split
    convert_x<<<2048, 256, 0, stream>>>(x, xhi, xlo);
    // S1: weight transposes (all hi-only now; FF was hi-only in R5 already)
    convert_wt<<<dim3(16, 48, 2), 256, 0, stream>>>(wqkv[0], wqkv[1], wqh, nullptr, 786432, 1536, 0);
    convert_wt<<<dim3(16, 16, 2), 256, 0, stream>>>(w1[0], w1[1], w1h, nullptr, 1048576, 512, 0);
    convert_wt<<<dim3(16, 16, 2), 256, 0, stream>>>(w2[0], w2[1], w2h, nullptr, 1048576, 512, 0);
    // S2: qkv gemm — 2-term (x hi/lo × w-hi), R5-proven TERMS=2 path
    gemm_split<128, 2, 0><<<dim3(32, 12, 2), 256, 0, stream>>>(
        xhi, xlo, 0, wqh, nullptr, 786432, bqkv[0], bqkv[1], 1536,
        Qb, Kb, Vt, nullptr, nullptr, nullptr, nullptr);
    // S3: attention (both layers; z=0 causal, z=1 anti-causal)
    attn_mfma<<<dim3(32, 16, 2), 256, 0, stream>>>(Qb, Kb, Vt, AO0, AO1);
    // S4: add + LN -> x1 hi/lo
    add_ln_a<<<dim3(1024, 1, 2), 256, 0, stream>>>(x, AO0, AO1,
        ga[0], ga[1], bea[0], bea[1], x1h, x1l, 4194304);
    // S5: ff1 (gelu) -> h hi/lo (in d_out), 2-term
    gemm_split<64, 2, 1><<<dim3(64, 4, 2), 256, 0, stream>>>(
        x1h, x1l, 4194304, w1h, nullptr, 1048576, b1[0], b1[1], 512,
        nullptr, nullptr, nullptr, h0h, h1h, h0l, h1l);
    // S6: ff2 -> ffo hi/lo (in ws), 2-term
    gemm_split<64, 2, 2><<<dim3(64, 4, 2), 256, 0, stream>>>(
        h0h, h0l, 4194304, w2h, nullptr, 1048576, b2[0], b2[1], 512,
        nullptr, nullptr, nullptr, ffo0h, ffo1h, ffo0l, ffo1l);
    // S7: add + LN + sigmoid -> td
    add_ln_b<<<dim3(1024, 1, 2), 256, 0, stream>>>(
        x1h, x1l, 4194304, ffo0h, ffo1h, ffo0l, ffo1l,
        gb[0], gb[1], beb[0], beb[1], td1, td2);
    // S8: sim
    sim_mfma<<<dim3(8, 8, 4), 256, 0, stream>>>(td1, td2, out);
}

// Round 8
// 179.992 us; speedup vs baseline: 12.6663x; 1.0071x over previous
//
#include <hip/hip_runtime.h>
#include <math.h>

// ---------------------------------------------------------------------------
// bf16-MFMA implementation, both layers merged (z=2), global_load_lds staging.
//  - all dense GEMMs: 2-term split (A hi/lo × B hi) — R7-proven numerics
//  - attention + sim: plain bf16 MFMA
//  - BK=32 GEMM tiles, swizzle ch ^= (row>>1)&3 (R5/R7-proven, 0 conflicts)
//  - R8: double-buffered gll staging in all GEMMs (attn_mfma's proven pattern)
// ---------------------------------------------------------------------------

typedef float f32x4 __attribute__((ext_vector_type(4)));
typedef short s16x8 __attribute__((ext_vector_type(8)));
typedef unsigned short u16;
typedef unsigned int u32;

#define NTOK 1024
#define PL 512
#define QSCALE 0.04419417382415922f  // 1/sqrt(512)

__device__ inline u16 f2bf(float f) {
    unsigned u = __builtin_bit_cast(unsigned, f);
    unsigned r = u + 0x7fffu + ((u >> 16) & 1u);   // RNE
    return (u16)(r >> 16);
}
__device__ inline float bf2f(u16 h) {
    unsigned u = ((unsigned)h) << 16;
    return __builtin_bit_cast(float, u);
}

__device__ inline void gll16(const void* g, void* l) {
    __builtin_amdgcn_global_load_lds(
        (const __attribute__((address_space(1))) u32*)g,
        (__attribute__((address_space(3))) u32*)l, 16, 0, 0);
}

// ---------------------------------------------------------------------------
// x -> hi/lo bf16 split (elementwise)
// ---------------------------------------------------------------------------
__global__ __launch_bounds__(256) void convert_x(const float* __restrict__ X,
    u16* __restrict__ hi, u16* __restrict__ lo)
{
    const int i = (blockIdx.x * 256 + threadIdx.x) * 4;
    float4 v = *(const float4*)&X[i];
    float vv[4] = {v.x, v.y, v.z, v.w};
    #pragma unroll
    for (int j = 0; j < 4; j++) {
        u16 h = f2bf(vv[j]);
        hi[i + j] = h;
        lo[i + j] = f2bf(vv[j] - bf2f(h));
    }
}

// ---------------------------------------------------------------------------
// W [512][N] f32 -> Wt [N][512] bf16 hi (tiled transpose), z = layer
// ---------------------------------------------------------------------------
__global__ __launch_bounds__(256) void convert_wt(const float* __restrict__ W0,
    const float* __restrict__ W1, u16* __restrict__ WhiB, const size_t dLS, const int N)
{
    const float* W = blockIdx.z ? W1 : W0;
    u16* Whi = WhiB + (size_t)blockIdx.z * dLS;
    __shared__ float T[32][36];
    const int k0 = blockIdx.x * 32, n0 = blockIdx.y * 32;
    const int tr = threadIdx.x >> 3, tc = (threadIdx.x & 7) * 4;
    *(float4*)&T[tr][tc] = *(const float4*)&W[(size_t)(k0 + tr) * N + n0 + tc];
    __syncthreads();
    const size_t o = (size_t)(n0 + tr) * 512 + k0 + tc;
    #pragma unroll
    for (int j = 0; j < 4; j++) Whi[o + j] = f2bf(T[tc + j][tr]);
}

// ---------------------------------------------------------------------------
// 2-term split-bf16 MFMA GEMM, z = layer. A[4096][512] (hi/lo) x Bt[N][512] (hi).
// EPI: 0 = qkv scatter (Q scaled, K, Vt), 1 = gelu -> hi/lo, 2 = plain hi/lo.
// BK=32; double-buffered gll staging (stage kt+1 before compute kt, 1 barrier).
// ---------------------------------------------------------------------------
template<int BM, int EPI>
__global__ __launch_bounds__(256) void gemm_split(
    const u16* __restrict__ AhiB, const u16* __restrict__ AloB, const size_t aLS,
    const u16* __restrict__ BhiB, const size_t bLS,
    const float* __restrict__ bias0, const float* __restrict__ bias1, const int Ncols,
    u16* __restrict__ qq, u16* __restrict__ kkp, u16* __restrict__ vvp,
    u16* __restrict__ oh0, u16* __restrict__ oh1,
    u16* __restrict__ ol0, u16* __restrict__ ol1)
{
    constexpr int FM = BM / 32;
    __shared__ u16 Ah[2][BM * 32], Al[2][BM * 32], Bh[2][128 * 32];
    const int z = blockIdx.z;
    const u16* Ahi = AhiB + (size_t)z * aLS;
    const u16* Alo = AloB + (size_t)z * aLS;
    const u16* Bhi = BhiB + (size_t)z * bLS;
    const float* bias = z ? bias1 : bias0;
    u16* oh = z ? oh1 : oh0;
    u16* ol = z ? ol1 : ol0;

    const int t = threadIdx.x, l = t & 63, w = t >> 6;
    const int lr = l & 15, lg = l >> 4;
    const int wm = w >> 1, wn = w & 1;
    const int m0 = blockIdx.x * BM, n0 = blockIdx.y * 128;
    const int srow = l >> 2, sch = l & 3;    // staging lane coords (16 rows/KB)

    f32x4 acc[FM][4];
    #pragma unroll
    for (int i = 0; i < FM; i++)
        #pragma unroll
        for (int j = 0; j < 4; j++) acc[i][j] = f32x4{0.f, 0.f, 0.f, 0.f};

    auto stage = [&](int bufi, int k0) {
        #pragma unroll
        for (int i = 0; i < BM / 64; i++) {
            const int j = w * (BM / 64) + i;
            const int r = j * 16 + srow;
            const int ck = sch ^ ((r >> 1) & 3);
            const size_t g = (size_t)(m0 + r) * 512 + k0 + ck * 8;
            gll16(&Ahi[g], &Ah[bufi][j * 512]);
            gll16(&Alo[g], &Al[bufi][j * 512]);
        }
        #pragma unroll
        for (int i = 0; i < 2; i++) {
            const int j = w * 2 + i;
            const int r = j * 16 + srow;
            const int ck = sch ^ ((r >> 1) & 3);
            gll16(&Bhi[(size_t)(n0 + r) * 512 + k0 + ck * 8], &Bh[bufi][j * 512]);
        }
    };

    stage(0, 0);
    __syncthreads();
    int buf = 0;
    for (int kt = 0; kt < 16; kt++) {
        if (kt < 15) stage(buf ^ 1, (kt + 1) * 32);

        s16x8 ah[FM], al[FM];
        #pragma unroll
        for (int fm = 0; fm < FM; fm++) {
            const int r = wm * (BM / 2) + fm * 16 + lr;
            const int d = r * 32 + ((lg ^ ((r >> 1) & 3)) << 3);
            ah[fm] = *(const s16x8*)&Ah[buf][d];
            al[fm] = *(const s16x8*)&Al[buf][d];
        }
        #pragma unroll
        for (int fn = 0; fn < 4; fn++) {
            const int r = wn * 64 + fn * 16 + lr;
            const int d = r * 32 + ((lg ^ ((r >> 1) & 3)) << 3);
            s16x8 bh = *(const s16x8*)&Bh[buf][d];
            #pragma unroll
            for (int fm = 0; fm < FM; fm++) {
                acc[fm][fn] = __builtin_amdgcn_mfma_f32_16x16x32_bf16(ah[fm], bh, acc[fm][fn], 0, 0, 0);
                acc[fm][fn] = __builtin_amdgcn_mfma_f32_16x16x32_bf16(al[fm], bh, acc[fm][fn], 0, 0, 0);
            }
        }
        __syncthreads();   // waves done with buf; stage(buf^1) drained
        buf ^= 1;
    }
    // epilogue
    #pragma unroll
    for (int fm = 0; fm < FM; fm++)
        #pragma unroll
        for (int fn = 0; fn < 4; fn++)
            #pragma unroll
            for (int rg = 0; rg < 4; rg++) {
                const int r = m0 + wm * (BM / 2) + fm * 16 + lg * 4 + rg;
                const int c = n0 + wn * 64 + fn * 16 + lr;
                float v = acc[fm][fn][rg] + bias[c];
                if constexpr (EPI == 0) {
                    const int part = c >> 9, c2 = c & 511;
                    const int h = c2 & 7, dd = c2 >> 3;
                    const int b = r >> 10, n = r & 1023;
                    const size_t bh_ = (size_t)(b * 8 + h);
                    const size_t zo = (size_t)z * 2097152;
                    if (part == 0)      qq [zo + (bh_ * 1024 + n) * 64 + dd] = f2bf(v * QSCALE);
                    else if (part == 1) kkp[zo + (bh_ * 1024 + n) * 64 + dd] = f2bf(v);
                    else                vvp[zo + (bh_ * 64 + dd) * 1024 + n] = f2bf(v);
                } else {
                    float gl = v;
                    if constexpr (EPI == 1)
                        gl = 0.5f * v * (1.f + erff(v * 0.70710678118654752f));
                    u16 hv = f2bf(gl);
                    oh[(size_t)r * Ncols + c] = hv;
                    ol[(size_t)r * Ncols + c] = f2bf(gl - bf2f(hv));
                }
            }
}

// ---------------------------------------------------------------------------
// Flash attention, bf16 MFMA, z = layer (z==0 causal, z==1 anti-causal).
// K/Vt tiles staged in LDS via global_load_lds, double-buffered. (unchanged)
// ---------------------------------------------------------------------------
__global__ __launch_bounds__(256) void attn_mfma(const u16* __restrict__ Qg,
    const u16* __restrict__ Kg, const u16* __restrict__ Vtg,
    float* __restrict__ AO0, float* __restrict__ AO1)
{
    __shared__ u16 Ks[2][64 * 64];
    __shared__ u16 Vs[2][64 * 64];
    __shared__ u16 Ps[4][16 * 72];
    const int t = threadIdx.x, l = t & 63, w = t >> 6;
    const int lr = l & 15, lg = l >> 4;
    const int z = blockIdx.z;
    const int causal = (z == 0);
    const int bh = blockIdx.x;
    const int b = bh >> 3, h = bh & 7;
    const int qt = causal ? (15 - (int)blockIdx.y) : (int)blockIdx.y;  // long jobs first
    const u16* Qb = Qg + (size_t)(z * 32 + bh) * (NTOK * 64);
    const u16* Kb = Kg + (size_t)(z * 32 + bh) * (NTOK * 64);
    const u16* Vb = Vtg + (size_t)(z * 32 + bh) * (64 * NTOK);
    float* AO = z ? AO1 : AO0;
    const int q0 = qt * 64 + w * 16;

    s16x8 aq[2];
    aq[0] = *(const s16x8*)&Qb[(size_t)(q0 + lr) * 64 + lg * 8];
    aq[1] = *(const s16x8*)&Qb[(size_t)(q0 + lr) * 64 + 32 + lg * 8];

    f32x4 o[4];
    float m_[4], l_[4];
    #pragma unroll
    for (int f = 0; f < 4; f++) o[f] = f32x4{0.f, 0.f, 0.f, 0.f};
    #pragma unroll
    for (int r = 0; r < 4; r++) { m_[r] = -INFINITY; l_[r] = 0.f; }

    const int kt0 = causal ? 0 : qt, kt1 = causal ? qt : 15;

    auto stage = [&](int bufi, int kt) {
        #pragma unroll
        for (int i = 0; i < 2; i++) {
            const int j = w * 2 + i;
            const int r = j * 8 + (l >> 3);
            const int ck = (l & 7) ^ (r & 7);
            gll16(Kb + (size_t)(kt * 64 + r) * 64 + ck * 8, &Ks[bufi][j * 512]);
        }
        #pragma unroll
        for (int i = 0; i < 2; i++) {
            const int j = w * 2 + i;
            const int dim = j * 8 + (l >> 3);
            const int ck = (l & 7) ^ (dim & 7);
            gll16(Vb + (size_t)dim * NTOK + kt * 64 + ck * 8, &Vs[bufi][j * 512]);
        }
    };

    stage(0, kt0);
    __syncthreads();
    int buf = 0;
    for (int kt = kt0; kt <= kt1; kt++) {
        if (kt < kt1) stage(buf ^ 1, kt + 1);
        f32x4 s[4];
        #pragma unroll
        for (int f = 0; f < 4; f++) s[f] = f32x4{0.f, 0.f, 0.f, 0.f};
        #pragma unroll
        for (int kk = 0; kk < 2; kk++)
            #pragma unroll
            for (int f = 0; f < 4; f++) {
                const int row = f * 16 + lr;
                const int ch = kk * 4 + lg;
                s16x8 bk = *(const s16x8*)&Ks[buf][row * 64 + ((ch ^ (row & 7)) << 3)];
                s[f] = __builtin_amdgcn_mfma_f32_16x16x32_bf16(aq[kk], bk, s[f], 0, 0, 0);
            }
        if (kt == qt) {
            #pragma unroll
            for (int f = 0; f < 4; f++) {
                const int key = kt * 64 + f * 16 + lr;
                #pragma unroll
                for (int r = 0; r < 4; r++) {
                    const int q = q0 + lg * 4 + r;
                    if (causal ? (key > q) : (key < q)) s[f][r] = -INFINITY;
                }
            }
        }
        float scale[4];
        #pragma unroll
        for (int r = 0; r < 4; r++) {
            float rm = fmaxf(fmaxf(s[0][r], s[1][r]), fmaxf(s[2][r], s[3][r]));
            #pragma unroll
            for (int off = 1; off < 16; off <<= 1) rm = fmaxf(rm, __shfl_xor(rm, off));
            const float mn = fmaxf(m_[r], rm);
            scale[r] = __expf(m_[r] - mn);
            float ps = 0.f;
            #pragma unroll
            for (int f = 0; f < 4; f++) { float p = __expf(s[f][r] - mn); s[f][r] = p; ps += p; }
            #pragma unroll
            for (int off = 1; off < 16; off <<= 1) ps += __shfl_xor(ps, off);
            l_[r] = l_[r] * scale[r] + ps;
            m_[r] = mn;
        }
        #pragma unroll
        for (int f = 0; f < 4; f++)
            #pragma unroll
            for (int r = 0; r < 4; r++)
                Ps[w][(lg * 4 + r) * 72 + f * 16 + lr] = f2bf(s[f][r]);
        #pragma unroll
        for (int f = 0; f < 4; f++)
            #pragma unroll
            for (int r = 0; r < 4; r++) o[f][r] *= scale[r];
        #pragma unroll
        for (int kk = 0; kk < 2; kk++) {
            s16x8 ap = *(const s16x8*)&Ps[w][lr * 72 + kk * 32 + lg * 8];
            #pragma unroll
            for (int f = 0; f < 4; f++) {
                const int row = f * 16 + lr;
                const int ch = kk * 4 + lg;
                s16x8 bv = *(const s16x8*)&Vs[buf][row * 64 + ((ch ^ (row & 7)) << 3)];
                o[f] = __builtin_amdgcn_mfma_f32_16x16x32_bf16(ap, bv, o[f], 0, 0, 0);
            }
        }
        __syncthreads();
        buf ^= 1;
    }
    #pragma unroll
    for (int f = 0; f < 4; f++)
        #pragma unroll
        for (int r = 0; r < 4; r++)
            AO[(size_t)(b * NTOK + q0 + lg * 4 + r) * PL + h * 64 + f * 16 + lr] = o[f][r] / l_[r];
}

// ---------------------------------------------------------------------------
// add+LN A: x(f32)+attn(f32) -> LN -> hi/lo bf16. z = layer.
// ---------------------------------------------------------------------------
__global__ __launch_bounds__(256) void add_ln_a(const float* __restrict__ X,
    const float* __restrict__ A0, const float* __restrict__ A1,
    const float* __restrict__ g0, const float* __restrict__ g1,
    const float* __restrict__ be0, const float* __restrict__ be1,
    u16* __restrict__ OhiB, u16* __restrict__ OloB, const size_t oLS)
{
    const int z = blockIdx.z;
    const float* A = z ? A1 : A0;
    const float* g = z ? g1 : g0;
    const float* be = z ? be1 : be0;
    u16* Ohi = OhiB + (size_t)z * oLS;
    u16* Olo = OloB + (size_t)z * oLS;
    const int row = blockIdx.x * 4 + (threadIdx.x >> 6);
    const int lane = threadIdx.x & 63;
    const float* xr = X + (size_t)row * PL;
    const float* ar = A + (size_t)row * PL;
    float v[8];
    float sum = 0.f;
    #pragma unroll
    for (int u = 0; u < 8; u++) { v[u] = xr[lane + u * 64] + ar[lane + u * 64]; sum += v[u]; }
    #pragma unroll
    for (int o = 32; o > 0; o >>= 1) sum += __shfl_xor(sum, o);
    const float mu = sum * (1.f / 512.f);
    float s2 = 0.f;
    #pragma unroll
    for (int u = 0; u < 8; u++) { float d = v[u] - mu; s2 = fmaf(d, d, s2); }
    #pragma unroll
    for (int o = 32; o > 0; o >>= 1) s2 += __shfl_xor(s2, o);
    const float rstd = rsqrtf(s2 * (1.f / 512.f) + 1e-5f);
    #pragma unroll
    for (int u = 0; u < 8; u++) {
        const int c = lane + u * 64;
        float y = (v[u] - mu) * rstd * g[c] + be[c];
        u16 hv = f2bf(y);
        Ohi[(size_t)row * PL + c] = hv;
        Olo[(size_t)row * PL + c] = f2bf(y - bf2f(hv));
    }
}

// ---------------------------------------------------------------------------
// add+LN B: (x1 hi+lo) + (ff hi+lo) -> LN -> sigmoid -> bf16 td. z = layer.
// ---------------------------------------------------------------------------
__global__ __launch_bounds__(256) void add_ln_b(
    const u16* __restrict__ XhiB, const u16* __restrict__ XloB, const size_t xLS,
    const u16* __restrict__ F0h, const u16* __restrict__ F1h,
    const u16* __restrict__ F0l, const u16* __restrict__ F1l,
    const float* __restrict__ g0, const float* __restrict__ g1,
    const float* __restrict__ be0, const float* __restrict__ be1,
    u16* __restrict__ TD0, u16* __restrict__ TD1)
{
    const int z = blockIdx.z;
    const u16* Xhi = XhiB + (size_t)z * xLS;
    const u16* Xlo = XloB + (size_t)z * xLS;
    const u16* Fh = z ? F1h : F0h;
    const u16* Fl = z ? F1l : F0l;
    const float* g = z ? g1 : g0;
    const float* be = z ? be1 : be0;
    u16* TD = z ? TD1 : TD0;
    const int row = blockIdx.x * 4 + (threadIdx.x >> 6);
    const int lane = threadIdx.x & 63;
    const size_t ro = (size_t)row * PL;
    float v[8];
    float sum = 0.f;
    #pragma unroll
    for (int u = 0; u < 8; u++) {
        const int c = lane + u * 64;
        v[u] = bf2f(Xhi[ro + c]) + bf2f(Xlo[ro + c]) + bf2f(Fh[ro + c]) + bf2f(Fl[ro + c]);
        sum += v[u];
    }
    #pragma unroll
    for (int o = 32; o > 0; o >>= 1) sum += __shfl_xor(sum, o);
    const float mu = sum * (1.f / 512.f);
    float s2 = 0.f;
    #pragma unroll
    for (int u = 0; u < 8; u++) { float d = v[u] - mu; s2 = fmaf(d, d, s2); }
    #pragma unroll
    for (int o = 32; o > 0; o >>= 1) s2 += __shfl_xor(s2, o);
    const float rstd = rsqrtf(s2 * (1.f / 512.f) + 1e-5f);
    #pragma unroll
    for (int u = 0; u < 8; u++) {
        const int c = lane + u * 64;
        float y = (v[u] - mu) * rstd * g[c] + be[c];
        TD[ro + c] = f2bf(1.f / (1.f + expf(-y)));
    }
}

// ---------------------------------------------------------------------------
// sim: per batch, C[i][j] = dot(td1[i,:], td2[j,:]) / 512  (plain bf16 MFMA)
// gll-staged, BK=64, double-buffered.
// ---------------------------------------------------------------------------
__global__ __launch_bounds__(256) void sim_mfma(const u16* __restrict__ TD1,
    const u16* __restrict__ TD2, float* __restrict__ Out)
{
    __shared__ u16 Ah[2][128 * 64], Bh[2][128 * 64];
    const int t = threadIdx.x, l = t & 63, w = t >> 6;
    const int lr = l & 15, lg = l >> 4;
    const int wm = w >> 1, wn = w & 1;
    const int bz = blockIdx.z;
    const u16* A = TD1 + (size_t)bz * NTOK * PL;
    const u16* B = TD2 + (size_t)bz * NTOK * PL;
    const int m0 = blockIdx.x * 128, n0 = blockIdx.y * 128;

    f32x4 acc[4][4];
    #pragma unroll
    for (int i = 0; i < 4; i++)
        #pragma unroll
        for (int j = 0; j < 4; j++) acc[i][j] = f32x4{0.f, 0.f, 0.f, 0.f};

    auto stage = [&](int bufi, int k0) {
        #pragma unroll
        for (int i = 0; i < 4; i++) {
            const int j = w * 4 + i;
            const int r = j * 8 + (l >> 3);
            const int ck = (l & 7) ^ (r & 7);
            gll16(&A[(size_t)(m0 + r) * 512 + k0 + ck * 8], &Ah[bufi][j * 512]);
            gll16(&B[(size_t)(n0 + r) * 512 + k0 + ck * 8], &Bh[bufi][j * 512]);
        }
    };

    stage(0, 0);
    __syncthreads();
    int buf = 0;
    for (int kt = 0; kt < 8; kt++) {
        if (kt < 7) stage(buf ^ 1, (kt + 1) * 64);
        #pragma unroll
        for (int kk = 0; kk < 2; kk++) {
            const int ch = kk * 4 + lg;
            s16x8 af[4], bf[4];
            #pragma unroll
            for (int fm = 0; fm < 4; fm++) {
                const int r = wm * 64 + fm * 16 + lr;
                af[fm] = *(const s16x8*)&Ah[buf][r * 64 + ((ch ^ (r & 7)) << 3)];
            }
            #pragma unroll
            for (int fn = 0; fn < 4; fn++) {
                const int r = wn * 64 + fn * 16 + lr;
                bf[fn] = *(const s16x8*)&Bh[buf][r * 64 + ((ch ^ (r & 7)) << 3)];
            }
            #pragma unroll
            for (int fm = 0; fm < 4; fm++)
                #pragma unroll
                for (int fn = 0; fn < 4; fn++)
                    acc[fm][fn] = __builtin_amdgcn_mfma_f32_16x16x32_bf16(af[fm], bf[fn], acc[fm][fn], 0, 0, 0);
        }
        __syncthreads();
        buf ^= 1;
    }
    #pragma unroll
    for (int fm = 0; fm < 4; fm++)
        #pragma unroll
        for (int fn = 0; fn < 4; fn++)
            #pragma unroll
            for (int rg = 0; rg < 4; rg++) {
                const int r = m0 + wm * 64 + fm * 16 + lg * 4 + rg;
                const int c = n0 + wn * 64 + fn * 16 + lr;
                Out[((size_t)(bz * NTOK + r)) * NTOK + c] = acc[fm][fn][rg] * (1.f / 512.f);
            }
}

// ---------------------------------------------------------------------------
extern "C" void kernel_launch(void* const* d_in, const int* in_sizes, int n_in,
                              void* d_out, int out_size, void* d_ws, size_t ws_size,
                              hipStream_t stream)
{
    const float* x = (const float*)d_in[0];
    const float* wqkv[2] = {(const float*)d_in[1],  (const float*)d_in[11]};
    const float* bqkv[2] = {(const float*)d_in[2],  (const float*)d_in[12]};
    const float* ga[2]   = {(const float*)d_in[3],  (const float*)d_in[13]};
    const float* bea[2]  = {(const float*)d_in[4],  (const float*)d_in[14]};
    const float* w1[2]   = {(const float*)d_in[5],  (const float*)d_in[15]};
    const float* b1[2]   = {(const float*)d_in[6],  (const float*)d_in[16]};
    const float* w2[2]   = {(const float*)d_in[7],  (const float*)d_in[17]};
    const float* b2[2]   = {(const float*)d_in[8],  (const float*)d_in[18]};
    const float* gb[2]   = {(const float*)d_in[9],  (const float*)d_in[19]};
    const float* beb[2]  = {(const float*)d_in[10], (const float*)d_in[20]};

    // -------- workspace map (KB offsets; identical to R7's proven layout) --
    char* wsb = (char*)d_ws;
    char* ob  = (char*)d_out;
    #define WSK(kb) ((char*)wsb + ((size_t)(kb) << 10))
    #define OBK(kb) ((char*)ob  + ((size_t)(kb) << 10))
    // ws: [0,4M) wff (S1-S6) -> td1 (S7-)
    u16* w1h = (u16*)WSK(0);      // + z*1048576 elems
    u16* w2h = (u16*)WSK(1024);
    u16* td1 = (u16*)WSK(0);
    // ws: [4M,12M) xsplit (S0-S2) -> AO0 f32 (S3-S4) -> ffo0 hi/lo (S6-S7)
    u16*   xhi  = (u16*)WSK(4096);
    u16*   xlo  = (u16*)WSK(8192);
    float* AO0  = (float*)WSK(4096);
    u16*   ffo0h = (u16*)WSK(4096);
    u16*   ffo0l = (u16*)WSK(8192);
    // ws: [12M,18M) wq hi (S1-S2); [12M,16M) ffo1hi (S6-S7)
    u16* wqh = (u16*)WSK(12288);  // + z*786432 elems
    u16* ffo1h = (u16*)WSK(12288);
    // ws: [16M,32M) x1 hi/lo (S4-S7)
    u16* x1h = (u16*)WSK(16384);  // + z*4194304 elems
    u16* x1l = (u16*)WSK(20480);
    // ws: [18M,34M) Q,K (S2-S3)
    u16* Qb = (u16*)WSK(18432);   // + z*2097152 elems
    u16* Kb = (u16*)WSK(26624);
    // ws: [32M,36M) ffo1lo (S6-S7); [36M,40M) td2 (S7-)
    u16* ffo1l = (u16*)WSK(32768);
    u16* td2   = (u16*)WSK(36864);
    // d_out: Vt (S2-S3); AO1 (S3-S4); h hi/lo (S5-S6); final out (S8)
    u16*   Vt  = (u16*)OBK(0);    // + z*2097152 elems
    float* AO1 = (float*)OBK(8192);
    u16*   h0h = (u16*)OBK(0);
    u16*   h0l = (u16*)OBK(4096);
    u16*   h1h = (u16*)OBK(8192);
    u16*   h1l = (u16*)OBK(12288);
    float* out = (float*)d_out;

    // S0: x split
    convert_x<<<2048, 256, 0, stream>>>(x, xhi, xlo);
    // S1: weight transposes (hi only)
    convert_wt<<<dim3(16, 48, 2), 256, 0, stream>>>(wqkv[0], wqkv[1], wqh, 786432, 1536);
    convert_wt<<<dim3(16, 16, 2), 256, 0, stream>>>(w1[0], w1[1], w1h, 1048576, 512);
    convert_wt<<<dim3(16, 16, 2), 256, 0, stream>>>(w2[0], w2[1], w2h, 1048576, 512);
    // S2: qkv gemm — 2-term (x hi/lo × w-hi), dbuf
    gemm_split<128, 0><<<dim3(32, 12, 2), 256, 0, stream>>>(
        xhi, xlo, 0, wqh, 786432, bqkv[0], bqkv[1], 1536,
        Qb, Kb, Vt, nullptr, nullptr, nullptr, nullptr);
    // S3: attention (both layers; z=0 causal, z=1 anti-causal)
    attn_mfma<<<dim3(32, 16, 2), 256, 0, stream>>>(Qb, Kb, Vt, AO0, AO1);
    // S4: add + LN -> x1 hi/lo
    add_ln_a<<<dim3(1024, 1, 2), 256, 0, stream>>>(x, AO0, AO1,
        ga[0], ga[1], bea[0], bea[1], x1h, x1l, 4194304);
    // S5: ff1 (gelu) -> h hi/lo (in d_out), 2-term dbuf
    gemm_split<64, 1><<<dim3(64, 4, 2), 256, 0, stream>>>(
        x1h, x1l, 4194304, w1h, 1048576, b1[0], b1[1], 512,
        nullptr, nullptr, nullptr, h0h, h1h, h0l, h1l);
    // S6: ff2 -> ffo hi/lo (in ws), 2-term dbuf
    gemm_split<64, 2><<<dim3(64, 4, 2), 256, 0, stream>>>(
        h0h, h0l, 4194304, w2h, 1048576, b2[0], b2[1], 512,
        nullptr, nullptr, nullptr, ffo0h, ffo1h, ffo0l, ffo1l);
    // S7: add + LN + sigmoid -> td
    add_ln_b<<<dim3(1024, 1, 2), 256, 0, stream>>>(
        x1h, x1l, 4194304, ffo0h, ffo1h, ffo0l, ffo1l,
        gb[0], gb[1], beb[0], beb[1], td1, td2);
    // S8: sim
    sim_mfma<<<dim3(8, 8, 4), 256, 0, stream>>>(td1, td2, out);
}